// Round 12
// baseline (398.762 us; speedup 1.0000x reference)
//
#include <hip/hip_runtime.h>
#include <math.h>

// ---------------------------------------------------------------------------
// Shapes: 5 streams x B=2 x N=1024 x C=768; H=12 heads x D=64; AD=8; HID=3072
// TOK = 5*2*1024 = 10240 rows everywhere.
// ---------------------------------------------------------------------------
typedef __bf16 bf16;
typedef __attribute__((ext_vector_type(8))) __bf16 bf16x8;
typedef __attribute__((ext_vector_type(4))) __bf16 bf16x4;
typedef __attribute__((ext_vector_type(4))) float f32x4;
typedef __attribute__((ext_vector_type(16))) float f32x16;

#define TOK   10240
#define CD    768
#define NQKV  2304
#define NHID  3072
#define SEQ   1024
#define NH    12

__device__ __forceinline__ f32x4 mfma16(bf16x8 a, bf16x8 b, f32x4 c) {
  return __builtin_amdgcn_mfma_f32_16x16x32_bf16(a, b, c, 0, 0, 0);
}
__device__ __forceinline__ f32x16 mfma32(bf16x8 a, bf16x8 b, f32x16 c) {
  return __builtin_amdgcn_mfma_f32_32x32x16_bf16(a, b, c, 0, 0, 0);
}

// async global->LDS, 16B per lane. LDS dest must be wave-uniform base;
// HW writes at base + lane*16. Global src is per-lane.
__device__ __forceinline__ void gload16(const void* g, void* l) {
  __builtin_amdgcn_global_load_lds(
      (const __attribute__((address_space(1))) void*)g,
      (__attribute__((address_space(3))) void*)l, 16, 0, 0);
}

__device__ __forceinline__ unsigned pack2(bf16 a, bf16 b) {
  union { unsigned short u[2]; unsigned v; } x;
  x.u[0] = __builtin_bit_cast(unsigned short, a);
  x.u[1] = __builtin_bit_cast(unsigned short, b);
  return x.v;
}

__device__ __forceinline__ f32x4 b4tof(const bf16* p) {
  bf16x4 v = *(const bf16x4*)p;
  f32x4 r;
#pragma unroll
  for (int j = 0; j < 4; ++j) r[j] = (float)v[j];
  return r;
}

// tanh-approx GELU (abs err ~3e-3, fine vs 0.11 threshold); __expf is HW exp
__device__ __forceinline__ float fast_gelu(float v) {
  float u = 0.7978845608f * (v + 0.044715f * v * v * v);
  float e = __expf(fminf(2.f * u, 30.f));
  return 0.5f * v * (1.f + (e - 1.f) / (e + 1.f));
}

// ---------------------------------------------------------------------------
// Adapter math on 12 per-lane f32 values (cols 4*lane + 256*i + j).
// h1 reduce is over all 768 cols -> any lane->col partition works.
// ---------------------------------------------------------------------------
__device__ __forceinline__ void adapter_rows(
    const f32x4 xv[3], int lane, const float* __restrict__ dw,
    const float* __restrict__ db, const float* __restrict__ mw,
    const float* __restrict__ mb, const float* __restrict__ uw,
    const float* __restrict__ ub, bf16* __restrict__ orow) {
  float h1[8] = {0, 0, 0, 0, 0, 0, 0, 0};
#pragma unroll
  for (int i = 0; i < 3; ++i) {
#pragma unroll
    for (int j = 0; j < 4; ++j) {
      const int c = lane * 4 + 256 * i + j;
      const f32x4* dr = (const f32x4*)(dw + (size_t)c * 8);
      const f32x4 d0 = dr[0], d1 = dr[1];
      const float x = xv[i][j];
#pragma unroll
      for (int k = 0; k < 4; ++k) {
        h1[k] += x * d0[k];
        h1[4 + k] += x * d1[k];
      }
    }
  }
#pragma unroll
  for (int m = 1; m < 64; m <<= 1)
#pragma unroll
    for (int j = 0; j < 8; ++j) h1[j] += __shfl_xor(h1[j], m);
#pragma unroll
  for (int j = 0; j < 8; ++j) h1[j] += db[j];
  float h2[8];
#pragma unroll
  for (int k = 0; k < 8; ++k) {
    float v = mb[k];
#pragma unroll
    for (int j = 0; j < 8; ++j) v += h1[j] * mw[j * 8 + k];
    h2[k] = v;
  }
#pragma unroll
  for (int i = 0; i < 3; ++i) {
    const int cb = lane * 4 + 256 * i;
    f32x4 acc = *(const f32x4*)(ub + cb);
#pragma unroll
    for (int k = 0; k < 8; ++k) {
      const f32x4 uv = *(const f32x4*)(uw + (size_t)k * CD + cb);
#pragma unroll
      for (int j = 0; j < 4; ++j) acc[j] += h2[k] * uv[j];
    }
    bf16x4 o;
#pragma unroll
    for (int j = 0; j < 4; ++j) o[j] = (bf16)acc[j];
    *(bf16x4*)(orow + cb) = o;
  }
}

// ---------------------------------------------------------------------------
// Batched weight convert+transpose: all 4 weights in ONE launch.
// ---------------------------------------------------------------------------
__global__ __launch_bounds__(256) void transpose_all(
    const float* __restrict__ qkv_w, const float* __restrict__ proj_w,
    const float* __restrict__ fc1_w, const float* __restrict__ fc2_w,
    bf16* __restrict__ o_qkv, bf16* __restrict__ o_proj,
    bf16* __restrict__ o_fc1, bf16* __restrict__ o_fc2) {
  __shared__ float tile[32][33];
  int b = blockIdx.x;
  const float* in;
  bf16* out;
  int K, N, tx, ty;
  if (b < 1728) {
    in = qkv_w; out = o_qkv; K = 768; N = 2304; tx = b % 72; ty = b / 72;
  } else if (b < 2304) {
    b -= 1728;
    in = proj_w; out = o_proj; K = 768; N = 768; tx = b % 24; ty = b / 24;
  } else if (b < 4608) {
    b -= 2304;
    in = fc1_w; out = o_fc1; K = 768; N = 3072; tx = b % 96; ty = b / 96;
  } else {
    b -= 4608;
    in = fc2_w; out = o_fc2; K = 3072; N = 768; tx = b % 24; ty = b / 24;
  }
  const int bn = tx * 32, bk = ty * 32;
  const int r = threadIdx.x >> 5, c = threadIdx.x & 31;
#pragma unroll
  for (int i = 0; i < 4; ++i)
    tile[r + 8 * i][c] = in[(size_t)(bk + r + 8 * i) * N + bn + c];
  __syncthreads();
#pragma unroll
  for (int i = 0; i < 4; ++i)
    out[(size_t)(bn + r + 8 * i) * K + bk + c] = (bf16)tile[c][r + 8 * i];
}

// ---------------------------------------------------------------------------
// LN over 5 stacked stream inputs -> bf16 n1 [TOK][768] + FUSED adapter-1
// (a1 = adapter(n1), computed from the LN row still in registers).
// ---------------------------------------------------------------------------
__global__ __launch_bounds__(256) void ln5_adapter(
    const float* __restrict__ x0, const float* __restrict__ x1,
    const float* __restrict__ x2, const float* __restrict__ x3,
    const float* __restrict__ x4, const float* __restrict__ g,
    const float* __restrict__ b, bf16* __restrict__ out,
    const float* __restrict__ dw, const float* __restrict__ db,
    const float* __restrict__ mw, const float* __restrict__ mb,
    const float* __restrict__ uw, const float* __restrict__ ub,
    bf16* __restrict__ a1out) {
  const int w = threadIdx.x >> 6, lane = threadIdx.x & 63;
  const int row = blockIdx.x * 4 + w;
  const int s = row >> 11, rem = row & 2047;
  const float* xp;
  switch (s) {
    case 0: xp = x0; break; case 1: xp = x1; break; case 2: xp = x2; break;
    case 3: xp = x3; break; default: xp = x4; break;
  }
  const f32x4* xr = (const f32x4*)(xp + (size_t)rem * CD);
  f32x4 v[3];
#pragma unroll
  for (int i = 0; i < 3; ++i) v[i] = xr[lane + 64 * i];
  float sum = 0.f;
#pragma unroll
  for (int i = 0; i < 3; ++i)
#pragma unroll
    for (int j = 0; j < 4; ++j) sum += v[i][j];
#pragma unroll
  for (int m = 32; m >= 1; m >>= 1) sum += __shfl_xor(sum, m);
  const float mu = sum * (1.f / 768.f);
  float vs = 0.f;
#pragma unroll
  for (int i = 0; i < 3; ++i)
#pragma unroll
    for (int j = 0; j < 4; ++j) { float d = v[i][j] - mu; vs += d * d; }
#pragma unroll
  for (int m = 32; m >= 1; m >>= 1) vs += __shfl_xor(vs, m);
  const float rstd = rsqrtf(vs * (1.f / 768.f) + 1e-5f);
  bf16* orow = out + (size_t)row * CD;
  f32x4 nv[3];
#pragma unroll
  for (int i = 0; i < 3; ++i) {
    const int c4 = lane + 64 * i;
    f32x4 gg = ((const f32x4*)g)[c4], bb = ((const f32x4*)b)[c4];
    bf16x4 o;
#pragma unroll
    for (int j = 0; j < 4; ++j) {
      nv[i][j] = (v[i][j] - mu) * rstd * gg[j] + bb[j];
      o[j] = (bf16)nv[i][j];
    }
    *(bf16x4*)(orow + c4 * 4) = o;
  }
  adapter_rows(nv, lane, dw, db, mw, mb, uw, ub, a1out + (size_t)row * CD);
}

// ---------------------------------------------------------------------------
// FUSED: ys = xs + (ao0+ao1 bf16 split-K partials) + cross(a1 bf16);
// write ys (bf16), ln2(ys) (bf16), and a2 = adapter(ln1(ys)) directly
// (ln1(ys) never materialized; a2 goes to a SEPARATE buffer than a1 to
// avoid the cross-row RW race).
// ---------------------------------------------------------------------------
__global__ __launch_bounds__(256) void fuse_res_ln_ad(
    const float* __restrict__ x0, const float* __restrict__ x1,
    const float* __restrict__ x2, const float* __restrict__ x3,
    const float* __restrict__ x4, const bf16* __restrict__ m01,
    const bf16* __restrict__ a, bf16* __restrict__ ys,
    const float* __restrict__ g1, const float* __restrict__ b1,
    const float* __restrict__ g2, const float* __restrict__ b2,
    bf16* __restrict__ o2, const float* __restrict__ dw,
    const float* __restrict__ db, const float* __restrict__ mw,
    const float* __restrict__ mb, const float* __restrict__ uw,
    const float* __restrict__ ub, bf16* __restrict__ a2out) {
  const int w = threadIdx.x >> 6, lane = threadIdx.x & 63;
  const int row = blockIdx.x * 4 + w;
  const int s = row >> 11, rem = row & 2047;
  const float* xp;
  switch (s) {
    case 0: xp = x0; break; case 1: xp = x1; break; case 2: xp = x2; break;
    case 3: xp = x3; break; default: xp = x4; break;
  }
  const f32x4* xr = (const f32x4*)(xp + (size_t)rem * CD);
  const bf16* p0 = m01 + (size_t)row * CD;
  const bf16* p1 = m01 + (size_t)TOK * CD + (size_t)row * CD;
  const bf16* am = a + (size_t)(row - 2048) * CD;
  const bf16* ap = a + (size_t)(row + 2048) * CD;
  f32x4 v[3];
#pragma unroll
  for (int i = 0; i < 3; ++i) {
    const int c4 = lane + 64 * i;
    f32x4 t = xr[c4] + b4tof(p0 + c4 * 4) + b4tof(p1 + c4 * 4);
    if (s > 0) t += b4tof(am + c4 * 4);
    if (s < 4) t += b4tof(ap + c4 * 4);
    v[i] = t;
  }
  bf16* yr = ys + (size_t)row * CD;
#pragma unroll
  for (int i = 0; i < 3; ++i) {
    const int c4 = lane + 64 * i;
    bf16x4 yo;
#pragma unroll
    for (int j = 0; j < 4; ++j) yo[j] = (bf16)v[i][j];
    *(bf16x4*)(yr + c4 * 4) = yo;
  }

  float sum = 0.f;
#pragma unroll
  for (int i = 0; i < 3; ++i)
#pragma unroll
    for (int j = 0; j < 4; ++j) sum += v[i][j];
#pragma unroll
  for (int m = 32; m >= 1; m >>= 1) sum += __shfl_xor(sum, m);
  const float mu = sum * (1.f / 768.f);
  float vs = 0.f;
#pragma unroll
  for (int i = 0; i < 3; ++i)
#pragma unroll
    for (int j = 0; j < 4; ++j) { float d = v[i][j] - mu; vs += d * d; }
#pragma unroll
  for (int m = 32; m >= 1; m >>= 1) vs += __shfl_xor(vs, m);
  const float rstd = rsqrtf(vs * (1.f / 768.f) + 1e-5f);
  bf16* r2 = o2 + (size_t)row * CD;
  f32x4 nv[3];
#pragma unroll
  for (int i = 0; i < 3; ++i) {
    const int c4 = lane + 64 * i;
    f32x4 gg1 = ((const f32x4*)g1)[c4], bb1 = ((const f32x4*)b1)[c4];
    f32x4 gg2 = ((const f32x4*)g2)[c4], bb2 = ((const f32x4*)b2)[c4];
    bf16x4 ob;
#pragma unroll
    for (int j = 0; j < 4; ++j) {
      const float n = (v[i][j] - mu) * rstd;
      nv[i][j] = n * gg1[j] + bb1[j];
      ob[j] = (bf16)(n * gg2[j] + bb2[j]);
    }
    *(bf16x4*)(r2 + c4 * 4) = ob;
  }
  adapter_rows(nv, lane, dw, db, mw, mb, uw, ub, a2out + (size_t)row * CD);
}

// ---------------------------------------------------------------------------
// GEMM 256x256, BK=64, 8 waves (2M x 4N), 8-phase schedule (T2+T3+T4+T5).
// Proven-best configuration (fc1 = 88 us measured, R5/R10/R11).
// EPI: 0 = f32 store, 1 = bf16 store, 2 = fast-GELU -> bf16 store
// ---------------------------------------------------------------------------
#define GBAR() __builtin_amdgcn_s_barrier()

#define LOADA(MH, BUF)                                                      \
  _Pragma("unroll") for (int m_ = 0; m_ < 4; ++m_) {                        \
    af[m_][0] =                                                             \
        *(const bf16x8*)&As[BUF][((MH)*128 + arow + m_ * 16) * 64 + ach0];  \
    af[m_][1] =                                                             \
        *(const bf16x8*)&As[BUF][((MH)*128 + arow + m_ * 16) * 64 + ach1];  \
  }

#define LOADB(DST, NH, BUF)                                                 \
  _Pragma("unroll") for (int n_ = 0; n_ < 2; ++n_) {                        \
    DST[n_][0] =                                                            \
        *(const bf16x8*)&Bs[BUF][(brow + (NH)*32 + n_ * 16) * 64 + ach0];   \
    DST[n_][1] =                                                            \
        *(const bf16x8*)&Bs[BUF][(brow + (NH)*32 + n_ * 16) * 64 + ach1];   \
  }

#define MFMA_PH(MH, NH, BF)                                                 \
  __builtin_amdgcn_s_setprio(1);                                            \
  _Pragma("unroll") for (int m_ = 0; m_ < 4; ++m_)                          \
  _Pragma("unroll") for (int n_ = 0; n_ < 2; ++n_) {                        \
    acc[(MH)*4 + m_][(NH)*2 + n_] =                                         \
        mfma16(af[m_][0], BF[n_][0], acc[(MH)*4 + m_][(NH)*2 + n_]);        \
    acc[(MH)*4 + m_][(NH)*2 + n_] =                                         \
        mfma16(af[m_][1], BF[n_][1], acc[(MH)*4 + m_][(NH)*2 + n_]);        \
  }                                                                         \
  __builtin_amdgcn_s_setprio(0);

template <int EPI>
__global__ __launch_bounds__(512, 2) void gemm256(
    const bf16* __restrict__ A, const bf16* __restrict__ Bt,
    const float* __restrict__ bias, void* __restrict__ Cout, int N, int Klen,
    int ldk, int nbn, int bpk, size_t kpstride) {
  __shared__ bf16 As[2][16384];
  __shared__ bf16 Bs[2][16384];
  const int t = threadIdx.x, lane = t & 63, w = t >> 6;
  const int wm = w >> 2, wn = w & 3;

  const int chunkg = gridDim.x >> 3;
  const int wg = (blockIdx.x & 7) * chunkg + (blockIdx.x >> 3);
  const int kp = wg / bpk, rem = wg % bpk;
  const int bm = rem / nbn, bn = rem % nbn;

  f32x4 acc[8][4] = {};

  const int srow = t >> 3;
  const int scol = ((t & 7) ^ (srow & 7)) << 3;
  const size_t koff = (size_t)kp * Klen;
  const bf16* Ab = A + (size_t)(bm * 256 + srow) * ldk + koff + scol;
  const bf16* Bb = Bt + (size_t)(bn * 256 + srow) * ldk + koff + scol;
  const size_t r64 = (size_t)64 * ldk;

  auto stage_a = [&](int buf, int h, int kt) {
    const bf16* g = Ab + (size_t)h * 128 * ldk + (size_t)kt * 64;
    gload16(g, &As[buf][h * 8192 + w * 512]);
    gload16(g + r64, &As[buf][h * 8192 + 4096 + w * 512]);
  };
  auto stage_b = [&](int buf, int h, int kt) {
    const bf16* g = Bb + (size_t)h * 128 * ldk + (size_t)kt * 64;
    gload16(g, &Bs[buf][h * 8192 + w * 512]);
    gload16(g + r64, &Bs[buf][h * 8192 + 4096 + w * 512]);
  };

  const int arow = wm * 64 + (lane & 15);
  const int brow = wn * 64 + (lane & 15);
  const int ach0 = (((lane >> 4) + 0) ^ (lane & 7)) << 3;
  const int ach1 = (((lane >> 4) + 4) ^ (lane & 7)) << 3;

  stage_a(0, 0, 0); stage_b(0, 0, 0); stage_b(0, 1, 0); stage_a(0, 1, 0);
  stage_a(1, 0, 1); stage_b(1, 0, 1);
  asm volatile("s_waitcnt vmcnt(4)" ::: "memory");
  GBAR();

  const int NT = Klen >> 6, NI = NT >> 1;
  bf16x8 af[4][2], bf0[2][2], bf1[2][2];

  for (int j = 0; j < NI; ++j) {
    const int tA = 2 * j, tB = 2 * j + 1;
    const bool notlast = (j + 1 < NI);

    LOADA(0, 0);
    LOADB(bf0, 0, 0);
    stage_b(1, 1, tB);
    GBAR();
    MFMA_PH(0, 0, bf0);
    GBAR();
    LOADB(bf1, 1, 0);
    stage_a(1, 1, tB);
    GBAR();
    MFMA_PH(0, 1, bf1);
    GBAR();
    LOADA(1, 0);
    if (notlast) stage_a(0, 0, tA + 2);
    GBAR();
    MFMA_PH(1, 0, bf0);
    GBAR();
    if (notlast) {
      stage_b(0, 0, tA + 2);
      asm volatile("s_waitcnt vmcnt(4)" ::: "memory");
    } else {
      asm volatile("s_waitcnt vmcnt(0)" ::: "memory");
    }
    GBAR();
    MFMA_PH(1, 1, bf1);
    GBAR();

    LOADA(0, 1);
    LOADB(bf0, 0, 1);
    if (notlast) stage_b(0, 1, tA + 2);
    GBAR();
    MFMA_PH(0, 0, bf0);
    GBAR();
    LOADB(bf1, 1, 1);
    if (notlast) stage_a(0, 1, tA + 2);
    GBAR();
    MFMA_PH(0, 1, bf1);
    GBAR();
    LOADA(1, 1);
    if (notlast) stage_a(1, 0, tB + 2);
    GBAR();
    MFMA_PH(1, 0, bf0);
    GBAR();
    if (notlast) {
      stage_b(1, 0, tB + 2);
      asm volatile("s_waitcnt vmcnt(4)" ::: "memory");
    }
    GBAR();
    MFMA_PH(1, 1, bf1);
    GBAR();
  }

#pragma unroll
  for (int am = 0; am < 8; ++am) {
    const int grow0 =
        bm * 256 + (am >> 2) * 128 + wm * 64 + (am & 3) * 16 + (lane >> 4) * 4;
#pragma unroll
    for (int an = 0; an < 4; ++an) {
      const int gcol = bn * 256 + wn * 64 + an * 16 + (lane & 15);
      const float bv = (kp == 0) ? bias[gcol] : 0.f;
#pragma unroll
      for (int r = 0; r < 4; ++r) {
        float v = acc[am][an][r] + bv;
        if (EPI == 2) v = fast_gelu(v);
        const size_t idx = (size_t)(grow0 + r) * N + gcol + kp * kpstride;
        if (EPI == 0) ((float*)Cout)[idx] = v;
        else ((bf16*)Cout)[idx] = (bf16)v;
      }
    }
  }
}

// ---------------------------------------------------------------------------
// Flash attention v2 — swapped-operand 32x32 MFMA, in-register softmax.
// log2-domain (Q pre-scaled by 0.125*log2e; exp2f = native v_exp) +
// defer-max (T13, THR=8 log2-units -> P <= 256, f32/bf16-safe).
// ---------------------------------------------------------------------------
__global__ __launch_bounds__(256, 4) void attn_v2(
    const bf16* __restrict__ qkv, bf16* __restrict__ obuf) {
  __shared__ bf16 Ks[2][4096];
  __shared__ bf16 Vt[2][4096];
  const int t = threadIdx.x, lane = t & 63, w = t >> 6;
  const int g = lane >> 5, q32 = lane & 31, rq7 = q32 & 7;

  const int xcd = blockIdx.x & 7, slot = blockIdx.x >> 3;
  const int work = xcd * 120 + slot;
  const int sbh = work >> 3, qt = work & 7;
  const int sb = sbh / NH, h = sbh % NH;
  const size_t tokbase = (size_t)sb * SEQ;
  const int qoff = h * 64, koff = CD + h * 64, voff = 2 * CD + h * 64;

  const int qrow = qt * 128 + w * 32 + q32;
  bf16x8 qf[4];
  {
    const bf16* qp = qkv + (tokbase + qrow) * NQKV + qoff + g * 8;
#pragma unroll
    for (int kd = 0; kd < 4; ++kd) {
      bf16x8 v = *(const bf16x8*)(qp + kd * 16);
#pragma unroll
      for (int j = 0; j < 8; ++j)
        v[j] = (bf16)((float)v[j] * 0.18033688f);  // 0.125 * log2(e)
      qf[kd] = v;
    }
  }

  const int skv1 = t >> 3, sc1 = (t & 7) ^ (skv1 & 7);
  const int skv2 = (t + 256) >> 3, sc2 = (t & 7) ^ (skv2 & 7);
  const int vkv0 = 2 * (t & 31);
  const int vd0 = 8 * (t >> 5);
  const int c0 = (vkv0 & 51) | ((vkv0 & 4) << 1) | ((vkv0 & 8) >> 1);
  const int vchunk = c0 >> 3, vsub = c0 & 7;
  const bf16* kbase = qkv + tokbase * NQKV + koff;
  const bf16* vbase = qkv + tokbase * NQKV + voff;

  {
    const bf16* kb0 = kbase;
    gload16(kb0 + (size_t)skv1 * NQKV + sc1 * 8, &Ks[0][w * 512]);
    gload16(kb0 + (size_t)skv2 * NQKV + sc2 * 8, &Ks[0][2048 + w * 512]);
    const bf16* vp = vbase + (size_t)vkv0 * NQKV + vd0;
    bf16x8 r0 = *(const bf16x8*)vp;
    bf16x8 r1 = *(const bf16x8*)(vp + NQKV);
#pragma unroll
    for (int j = 0; j < 8; ++j) {
      const int d = vd0 + j;
      *(unsigned*)&Vt[0][d * 64 + ((vchunk ^ j) << 3) + vsub] =
          pack2(r0[j], r1[j]);
    }
  }
  __syncthreads();

  float m_run = -1e30f, l_run = 0.f;
  f32x16 oT0 = {}, oT1 = {};
  int cur = 0;

  for (int kt = 0; kt < 16; ++kt) {
    bf16x8 nv0, nv1;
    if (kt < 15) {
      const bf16* vp = vbase + (size_t)((kt + 1) * 64 + vkv0) * NQKV + vd0;
      nv0 = *(const bf16x8*)vp;
      nv1 = *(const bf16x8*)(vp + NQKV);
      const bf16* kb0 = kbase + (size_t)(kt + 1) * 64 * NQKV;
      gload16(kb0 + (size_t)skv1 * NQKV + sc1 * 8, &Ks[cur ^ 1][w * 512]);
      gload16(kb0 + (size_t)skv2 * NQKV + sc2 * 8,
              &Ks[cur ^ 1][2048 + w * 512]);
    }

    f32x16 sT0 = {}, sT1 = {};
#pragma unroll
    for (int kd = 0; kd < 4; ++kd) {
      bf16x8 kf0 =
          *(const bf16x8*)&Ks[cur][q32 * 64 + (((2 * kd + g) ^ rq7) << 3)];
      bf16x8 kf1 = *(const bf16x8*)&Ks[cur][(32 + q32) * 64 +
                                            (((2 * kd + g) ^ rq7) << 3)];
      sT0 = mfma32(kf0, qf[kd], sT0);
      sT1 = mfma32(kf1, qf[kd], sT1);
    }

    float mt = sT0[0];
#pragma unroll
    for (int r = 1; r < 16; ++r) mt = fmaxf(mt, sT0[r]);
#pragma unroll
    for (int r = 0; r < 16; ++r) mt = fmaxf(mt, sT1[r]);
    mt = fmaxf(mt, __shfl_xor(mt, 32));
    // defer-max: only rescale when the running max grew by > 8 (log2 units)
    if (!__all(mt - m_run <= 8.f)) {
      const float mnew = fmaxf(m_run, mt);
      const float alpha = exp2f(m_run - mnew);
      l_run *= alpha;
#pragma unroll
      for (int r = 0; r < 16; ++r) { oT0[r] *= alpha; oT1[r] *= alpha; }
      m_run = mnew;
    }
    float rs = 0.f;
#pragma unroll
    for (int r = 0; r < 16; ++r) {
      sT0[r] = exp2f(sT0[r] - m_run);
      rs += sT0[r];
    }
#pragma unroll
    for (int r = 0; r < 16; ++r) {
      sT1[r] = exp2f(sT1[r] - m_run);
      rs += sT1[r];
    }
    rs += __shfl_xor(rs, 32);
    l_run += rs;

    bf16x8 pa[4];
#pragma unroll
    for (int hh = 0; hh < 2; ++hh)
#pragma unroll
      for (int j = 0; j < 8; ++j) {
        pa[hh][j] = (bf16)sT0[8 * hh + j];
        pa[2 + hh][j] = (bf16)sT1[8 * hh + j];
      }

#pragma unroll
    for (int ks = 0; ks < 4; ++ks) {
      bf16x8 vf0 =
          *(const bf16x8*)&Vt[cur][q32 * 64 + (((2 * ks + g) ^ rq7) << 3)];
      bf16x8 vf1 = *(const bf16x8*)&Vt[cur][(32 + q32) * 64 +
                                            (((2 * ks + g) ^ rq7) << 3)];
      oT0 = mfma32(vf0, pa[ks], oT0);
      oT1 = mfma32(vf1, pa[ks], oT1);
    }

    if (kt < 15) {
#pragma unroll
      for (int j = 0; j < 8; ++j) {
        const int d = vd0 + j;
        *(unsigned*)&Vt[cur ^ 1][d * 64 + ((vchunk ^ j) << 3) + vsub] =
            pack2(nv0[j], nv1[j]);
      }
    }
    __syncthreads();
    cur ^= 1;
  }

  const float rl = 1.f / l_run;
  bf16* orow = obuf + (tokbase + qrow) * CD + h * 64;
#pragma unroll
  for (int m = 0; m < 4; ++m) {
    bf16x4 o0, o1;
#pragma unroll
    for (int r = 0; r < 4; ++r) {
      o0[r] = (bf16)(oT0[4 * m + r] * rl);
      o1[r] = (bf16)(oT1[4 * m + r] * rl);
    }
    *(bf16x4*)(orow + 8 * m + 4 * g) = o0;
    *(bf16x4*)(orow + 32 + 8 * m + 4 * g) = o1;
  }
}

// ---------------------------------------------------------------------------
// Final: z[s] = ys[s](bf16) + m0[s] + m1[s] + cross(a2)   (out f32)
// ---------------------------------------------------------------------------
__global__ __launch_bounds__(256) void cross_residual(
    const bf16* __restrict__ ys, const bf16* __restrict__ m01,
    const bf16* __restrict__ a, float* __restrict__ out) {
  const int s = blockIdx.y;
  const size_t i = (size_t)blockIdx.x * 256 + threadIdx.x;  // group-of-4 index
  const size_t spitch = (size_t)2048 * 768 / 4;
  const size_t sb = (size_t)s * spitch;
  const size_t mstride = (size_t)TOK * CD / 4;
  f32x4 v = b4tof(ys + (sb + i) * 4);
  v += b4tof(m01 + (sb + i) * 4);
  v += b4tof(m01 + (mstride + sb + i) * 4);
  if (s > 0) v += b4tof(a + (sb - spitch + i) * 4);
  if (s < 4) v += b4tof(a + (sb + spitch + i) * 4);
  ((f32x4*)out)[sb + i] = v;
}

// ---------------------------------------------------------------------------
// workspace layout (bytes; ~203 MB)
// ---------------------------------------------------------------------------
#define OFF_WTQKV  ((size_t)0)           // bf16 [2304][768]
#define OFF_WTPROJ ((size_t)3538944)     // bf16 [768][768]
#define OFF_WTFC1  ((size_t)4718592)     // bf16 [3072][768]
#define OFF_WTFC2  ((size_t)9437184)     // bf16 [768][3072]
#define OFF_N1     ((size_t)14155776)    // bf16 [10240][768] n1; later a2
#define OFF_BIG    ((size_t)29884416)    // bf16 qkv [10240][2304]; later h
#define OFF_OBUF   ((size_t)77070336)    // bf16 o [10240][768]
#define OFF_AOM    ((size_t)92798976)    // bf16 partial pairs (proj, then fc2)
#define OFF_A12    ((size_t)124256256)   // bf16 [10240][768]: a1
#define OFF_YS     ((size_t)155713536)   // bf16 [10240][768] ys
#define OFF_L2Y    ((size_t)187170816)   // bf16 [10240][768]

extern "C" void kernel_launch(void* const* d_in, const int* in_sizes, int n_in,
                              void* d_out, int out_size, void* d_ws,
                              size_t ws_size, hipStream_t stream) {
  const float* x0 = (const float*)d_in[0];
  const float* x1 = (const float*)d_in[1];
  const float* x2 = (const float*)d_in[2];
  const float* x3 = (const float*)d_in[3];
  const float* x4 = (const float*)d_in[4];
  const float* ln1_g = (const float*)d_in[5];
  const float* ln1_b = (const float*)d_in[6];
  const float* ln2_g = (const float*)d_in[7];
  const float* ln2_b = (const float*)d_in[8];
  const float* qkv_w = (const float*)d_in[9];
  const float* qkv_b = (const float*)d_in[10];
  const float* proj_w = (const float*)d_in[11];
  const float* proj_b = (const float*)d_in[12];
  const float* fc1_w = (const float*)d_in[13];
  const float* fc1_b = (const float*)d_in[14];
  const float* fc2_w = (const float*)d_in[15];
  const float* fc2_b = (const float*)d_in[16];
  const float* at_dw = (const float*)d_in[17];
  const float* at_db = (const float*)d_in[18];
  const float* at_mw = (const float*)d_in[19];
  const float* at_mb = (const float*)d_in[20];
  const float* at_uw = (const float*)d_in[21];
  const float* at_ub = (const float*)d_in[22];
  const float* a2_dw = (const float*)d_in[23];
  const float* a2_db = (const float*)d_in[24];
  const float* a2_mw = (const float*)d_in[25];
  const float* a2_mb = (const float*)d_in[26];
  const float* a2_uw = (const float*)d_in[27];
  const float* a2_ub = (const float*)d_in[28];

  char* ws = (char*)d_ws;
  bf16* wt_qkv = (bf16*)(ws + OFF_WTQKV);
  bf16* wt_proj = (bf16*)(ws + OFF_WTPROJ);
  bf16* wt_fc1 = (bf16*)(ws + OFF_WTFC1);
  bf16* wt_fc2 = (bf16*)(ws + OFF_WTFC2);
  bf16* n1 = (bf16*)(ws + OFF_N1);
  bf16* a2b = (bf16*)(ws + OFF_N1);    // a2 reuses n1 region (dead by then)
  bf16* qkvb = (bf16*)(ws + OFF_BIG);
  bf16* obuf = (bf16*)(ws + OFF_OBUF);
  bf16* mbuf = (bf16*)(ws + OFF_AOM);  // split-K bf16 partial pair
  bf16* a1b = (bf16*)(ws + OFF_A12);
  bf16* ysb = (bf16*)(ws + OFF_YS);
  bf16* l2y = (bf16*)(ws + OFF_L2Y);

  const dim3 b256(256);
  const dim3 b512(512);

  // 1. all weight convert+transposes in one launch (6912 tiles)
  transpose_all<<<6912, b256, 0, stream>>>(qkv_w, proj_w, fc1_w, fc2_w,
                                           wt_qkv, wt_proj, wt_fc1, wt_fc2);

  // 2. n1 = LN(xs) (bf16) + a1 = adapter(n1)  (fused)
  ln5_adapter<<<2560, b256, 0, stream>>>(x0, x1, x2, x3, x4, ln1_g, ln1_b, n1,
                                         at_dw, at_db, at_mw, at_mb, at_uw,
                                         at_ub, a1b);

  // 3. qkv = n1 @ qkv_w + qkv_b  (bf16)   grid 40*9=360
  gemm256<1><<<360, b512, 0, stream>>>(n1, wt_qkv, qkv_b, qkvb, NQKV, 768, 768,
                                       9, 360, 0);

  // 4. attention -> o (bf16)
  attn_v2<<<960, b256, 0, stream>>>(qkvb, obuf);

  // 5. ao = o @ proj_w + proj_b  — split-K=2, bf16 partials (grid 240)
  gemm256<1><<<240, b512, 0, stream>>>(obuf, wt_proj, proj_b, mbuf, CD, 384,
                                       768, 3, 120, (size_t)TOK * CD);

  // 6. ys = xs + (ao0+ao1) + cross(a1) (bf16); ln2(ys)->l2y;
  //    a2 = adapter(ln1(ys)) -> a2b  (all fused; a2b != a1b, no race)
  fuse_res_ln_ad<<<2560, b256, 0, stream>>>(
      x0, x1, x2, x3, x4, mbuf, a1b, ysb, ln1_g, ln1_b, ln2_g, ln2_b, l2y,
      a2_dw, a2_db, a2_mw, a2_mb, a2_uw, a2_ub, a2b);

  // 7. h = gelu(ln2(ys) @ fc1_w + fc1_b)  (bf16)   grid 40*12=480
  gemm256<2><<<480, b512, 0, stream>>>(l2y, wt_fc1, fc1_b, qkvb, NHID, 768,
                                       768, 12, 480, 0);

  // 8. m = h @ fc2_w + fc2_b  — split-K=2, bf16 partials m0,m1
  gemm256<1><<<240, b512, 0, stream>>>(qkvb, wt_fc2, fc2_b, mbuf, CD, 1536,
                                       3072, 3, 120, (size_t)TOK * CD);

  // 9. z = ys + (m0+m1) + cross(a2) -> d_out
  cross_residual<<<dim3(1536, 5), b256, 0, stream>>>(ysb, mbuf, a2b,
                                                     (float*)d_out);
}

// Round 13
// 369.188 us; speedup vs baseline: 1.0801x; 1.0801x over previous
//
#include <hip/hip_runtime.h>
#include <math.h>

// ---------------------------------------------------------------------------
// Shapes: 5 streams x B=2 x N=1024 x C=768; H=12 heads x D=64; AD=8; HID=3072
// TOK = 5*2*1024 = 10240 rows everywhere.
// ---------------------------------------------------------------------------
typedef __bf16 bf16;
typedef __attribute__((ext_vector_type(8))) __bf16 bf16x8;
typedef __attribute__((ext_vector_type(4))) __bf16 bf16x4;
typedef __attribute__((ext_vector_type(4))) float f32x4;
typedef __attribute__((ext_vector_type(16))) float f32x16;

#define TOK   10240
#define CD    768
#define NQKV  2304
#define NHID  3072
#define SEQ   1024
#define NH    12

__device__ __forceinline__ f32x4 mfma16(bf16x8 a, bf16x8 b, f32x4 c) {
  return __builtin_amdgcn_mfma_f32_16x16x32_bf16(a, b, c, 0, 0, 0);
}
__device__ __forceinline__ f32x16 mfma32(bf16x8 a, bf16x8 b, f32x16 c) {
  return __builtin_amdgcn_mfma_f32_32x32x16_bf16(a, b, c, 0, 0, 0);
}

// async global->LDS, 16B per lane. LDS dest must be wave-uniform base;
// HW writes at base + lane*16. Global src is per-lane.
__device__ __forceinline__ void gload16(const void* g, void* l) {
  __builtin_amdgcn_global_load_lds(
      (const __attribute__((address_space(1))) void*)g,
      (__attribute__((address_space(3))) void*)l, 16, 0, 0);
}

__device__ __forceinline__ unsigned pack2(bf16 a, bf16 b) {
  union { unsigned short u[2]; unsigned v; } x;
  x.u[0] = __builtin_bit_cast(unsigned short, a);
  x.u[1] = __builtin_bit_cast(unsigned short, b);
  return x.v;
}

__device__ __forceinline__ f32x4 b4tof(const bf16* p) {
  bf16x4 v = *(const bf16x4*)p;
  f32x4 r;
#pragma unroll
  for (int j = 0; j < 4; ++j) r[j] = (float)v[j];
  return r;
}

// tanh-approx GELU (abs err ~3e-3, fine vs 0.11 threshold); __expf is HW exp
__device__ __forceinline__ float fast_gelu(float v) {
  float u = 0.7978845608f * (v + 0.044715f * v * v * v);
  float e = __expf(fminf(2.f * u, 30.f));
  return 0.5f * v * (1.f + (e - 1.f) / (e + 1.f));
}

// ---------------------------------------------------------------------------
// Batched weight convert+transpose: all 4 weights in ONE launch.
// ---------------------------------------------------------------------------
__global__ __launch_bounds__(256) void transpose_all(
    const float* __restrict__ qkv_w, const float* __restrict__ proj_w,
    const float* __restrict__ fc1_w, const float* __restrict__ fc2_w,
    bf16* __restrict__ o_qkv, bf16* __restrict__ o_proj,
    bf16* __restrict__ o_fc1, bf16* __restrict__ o_fc2) {
  __shared__ float tile[32][33];
  int b = blockIdx.x;
  const float* in;
  bf16* out;
  int K, N, tx, ty;
  if (b < 1728) {
    in = qkv_w; out = o_qkv; K = 768; N = 2304; tx = b % 72; ty = b / 72;
  } else if (b < 2304) {
    b -= 1728;
    in = proj_w; out = o_proj; K = 768; N = 768; tx = b % 24; ty = b / 24;
  } else if (b < 4608) {
    b -= 2304;
    in = fc1_w; out = o_fc1; K = 768; N = 3072; tx = b % 96; ty = b / 96;
  } else {
    b -= 4608;
    in = fc2_w; out = o_fc2; K = 3072; N = 768; tx = b % 24; ty = b / 24;
  }
  const int bn = tx * 32, bk = ty * 32;
  const int r = threadIdx.x >> 5, c = threadIdx.x & 31;
#pragma unroll
  for (int i = 0; i < 4; ++i)
    tile[r + 8 * i][c] = in[(size_t)(bk + r + 8 * i) * N + bn + c];
  __syncthreads();
#pragma unroll
  for (int i = 0; i < 4; ++i)
    out[(size_t)(bn + r + 8 * i) * K + bk + c] = (bf16)tile[c][r + 8 * i];
}

// ---------------------------------------------------------------------------
// LN over 5 stacked stream inputs -> bf16 [TOK][768]
// ---------------------------------------------------------------------------
__global__ __launch_bounds__(256) void ln5_kernel(
    const float* __restrict__ x0, const float* __restrict__ x1,
    const float* __restrict__ x2, const float* __restrict__ x3,
    const float* __restrict__ x4, const float* __restrict__ g,
    const float* __restrict__ b, bf16* __restrict__ out) {
  const int w = threadIdx.x >> 6, lane = threadIdx.x & 63;
  const int row = blockIdx.x * 4 + w;
  const int s = row >> 11, rem = row & 2047;
  const float* xp;
  switch (s) {
    case 0: xp = x0; break; case 1: xp = x1; break; case 2: xp = x2; break;
    case 3: xp = x3; break; default: xp = x4; break;
  }
  const f32x4* xr = (const f32x4*)(xp + (size_t)rem * CD);
  f32x4 v[3];
#pragma unroll
  for (int i = 0; i < 3; ++i) v[i] = xr[lane + 64 * i];
  float sum = 0.f;
#pragma unroll
  for (int i = 0; i < 3; ++i)
#pragma unroll
    for (int j = 0; j < 4; ++j) sum += v[i][j];
#pragma unroll
  for (int m = 32; m >= 1; m >>= 1) sum += __shfl_xor(sum, m);
  const float mu = sum * (1.f / 768.f);
  float vs = 0.f;
#pragma unroll
  for (int i = 0; i < 3; ++i)
#pragma unroll
    for (int j = 0; j < 4; ++j) { float d = v[i][j] - mu; vs += d * d; }
#pragma unroll
  for (int m = 32; m >= 1; m >>= 1) vs += __shfl_xor(vs, m);
  const float rstd = rsqrtf(vs * (1.f / 768.f) + 1e-5f);
  const f32x4* gp = (const f32x4*)g;
  const f32x4* bp = (const f32x4*)b;
  bf16* orow = out + (size_t)row * CD;
#pragma unroll
  for (int i = 0; i < 3; ++i) {
    const int c4 = lane + 64 * i;
    f32x4 gg = gp[c4], bb = bp[c4];
    bf16x4 o;
#pragma unroll
    for (int j = 0; j < 4; ++j)
      o[j] = (bf16)((v[i][j] - mu) * rstd * gg[j] + bb[j]);
    *(bf16x4*)(orow + c4 * 4) = o;
  }
}

// ---------------------------------------------------------------------------
// FUSED: ys = xs + (ao0+ao1 bf16 split-K partials) + cross(a1 bf16);
// write ys (bf16) + ln1(ys),ln2(ys) (bf16).
// ---------------------------------------------------------------------------
__global__ __launch_bounds__(256) void fuse_res_ln(
    const float* __restrict__ x0, const float* __restrict__ x1,
    const float* __restrict__ x2, const float* __restrict__ x3,
    const float* __restrict__ x4, const bf16* __restrict__ m01,
    const bf16* __restrict__ a, bf16* __restrict__ ys,
    const float* __restrict__ g1, const float* __restrict__ b1,
    const float* __restrict__ g2, const float* __restrict__ b2,
    bf16* __restrict__ o1, bf16* __restrict__ o2) {
  const int w = threadIdx.x >> 6, lane = threadIdx.x & 63;
  const int row = blockIdx.x * 4 + w;
  const int s = row >> 11, rem = row & 2047;
  const float* xp;
  switch (s) {
    case 0: xp = x0; break; case 1: xp = x1; break; case 2: xp = x2; break;
    case 3: xp = x3; break; default: xp = x4; break;
  }
  const f32x4* xr = (const f32x4*)(xp + (size_t)rem * CD);
  const bf16* p0 = m01 + (size_t)row * CD;
  const bf16* p1 = m01 + (size_t)TOK * CD + (size_t)row * CD;
  const bf16* am = a + (size_t)(row - 2048) * CD;
  const bf16* ap = a + (size_t)(row + 2048) * CD;
  f32x4 v[3];
#pragma unroll
  for (int i = 0; i < 3; ++i) {
    const int c4 = lane + 64 * i;
    f32x4 t = xr[c4] + b4tof(p0 + c4 * 4) + b4tof(p1 + c4 * 4);
    if (s > 0) t += b4tof(am + c4 * 4);
    if (s < 4) t += b4tof(ap + c4 * 4);
    v[i] = t;
  }
  bf16* yr = ys + (size_t)row * CD;
#pragma unroll
  for (int i = 0; i < 3; ++i) {
    const int c4 = lane + 64 * i;
    bf16x4 yo;
#pragma unroll
    for (int j = 0; j < 4; ++j) yo[j] = (bf16)v[i][j];
    *(bf16x4*)(yr + c4 * 4) = yo;
  }

  float sum = 0.f;
#pragma unroll
  for (int i = 0; i < 3; ++i)
#pragma unroll
    for (int j = 0; j < 4; ++j) sum += v[i][j];
#pragma unroll
  for (int m = 32; m >= 1; m >>= 1) sum += __shfl_xor(sum, m);
  const float mu = sum * (1.f / 768.f);
  float vs = 0.f;
#pragma unroll
  for (int i = 0; i < 3; ++i)
#pragma unroll
    for (int j = 0; j < 4; ++j) { float d = v[i][j] - mu; vs += d * d; }
#pragma unroll
  for (int m = 32; m >= 1; m >>= 1) vs += __shfl_xor(vs, m);
  const float rstd = rsqrtf(vs * (1.f / 768.f) + 1e-5f);
  bf16* r1 = o1 + (size_t)row * CD;
  bf16* r2 = o2 + (size_t)row * CD;
#pragma unroll
  for (int i = 0; i < 3; ++i) {
    const int c4 = lane + 64 * i;
    f32x4 gg1 = ((const f32x4*)g1)[c4], bb1 = ((const f32x4*)b1)[c4];
    f32x4 gg2 = ((const f32x4*)g2)[c4], bb2 = ((const f32x4*)b2)[c4];
    bf16x4 oa, ob;
#pragma unroll
    for (int j = 0; j < 4; ++j) {
      float n = (v[i][j] - mu) * rstd;
      oa[j] = (bf16)(n * gg1[j] + bb1[j]);
      ob[j] = (bf16)(n * gg2[j] + bb2[j]);
    }
    *(bf16x4*)(r1 + c4 * 4) = oa;
    *(bf16x4*)(r2 + c4 * 4) = ob;
  }
}

// ---------------------------------------------------------------------------
// GEMM 256x256, BK=64, 8 waves (2M x 4N), 8-phase schedule (T2+T3+T4+T5).
// Proven-best configuration (fc1 = 88 us measured, R5/R10/R11).
// EPI: 0 = f32 store, 1 = bf16 store, 2 = fast-GELU -> bf16 store
// ---------------------------------------------------------------------------
#define GBAR() __builtin_amdgcn_s_barrier()

#define LOADA(MH, BUF)                                                      \
  _Pragma("unroll") for (int m_ = 0; m_ < 4; ++m_) {                        \
    af[m_][0] =                                                             \
        *(const bf16x8*)&As[BUF][((MH)*128 + arow + m_ * 16) * 64 + ach0];  \
    af[m_][1] =                                                             \
        *(const bf16x8*)&As[BUF][((MH)*128 + arow + m_ * 16) * 64 + ach1];  \
  }

#define LOADB(DST, NH, BUF)                                                 \
  _Pragma("unroll") for (int n_ = 0; n_ < 2; ++n_) {                        \
    DST[n_][0] =                                                            \
        *(const bf16x8*)&Bs[BUF][(brow + (NH)*32 + n_ * 16) * 64 + ach0];   \
    DST[n_][1] =                                                            \
        *(const bf16x8*)&Bs[BUF][(brow + (NH)*32 + n_ * 16) * 64 + ach1];   \
  }

#define MFMA_PH(MH, NH, BF)                                                 \
  __builtin_amdgcn_s_setprio(1);                                            \
  _Pragma("unroll") for (int m_ = 0; m_ < 4; ++m_)                          \
  _Pragma("unroll") for (int n_ = 0; n_ < 2; ++n_) {                        \
    acc[(MH)*4 + m_][(NH)*2 + n_] =                                         \
        mfma16(af[m_][0], BF[n_][0], acc[(MH)*4 + m_][(NH)*2 + n_]);        \
    acc[(MH)*4 + m_][(NH)*2 + n_] =                                         \
        mfma16(af[m_][1], BF[n_][1], acc[(MH)*4 + m_][(NH)*2 + n_]);        \
  }                                                                         \
  __builtin_amdgcn_s_setprio(0);

template <int EPI>
__global__ __launch_bounds__(512, 2) void gemm256(
    const bf16* __restrict__ A, const bf16* __restrict__ Bt,
    const float* __restrict__ bias, void* __restrict__ Cout, int N, int Klen,
    int ldk, int nbn, int bpk, size_t kpstride) {
  __shared__ bf16 As[2][16384];
  __shared__ bf16 Bs[2][16384];
  const int t = threadIdx.x, lane = t & 63, w = t >> 6;
  const int wm = w >> 2, wn = w & 3;

  const int chunkg = gridDim.x >> 3;
  const int wg = (blockIdx.x & 7) * chunkg + (blockIdx.x >> 3);
  const int kp = wg / bpk, rem = wg % bpk;
  const int bm = rem / nbn, bn = rem % nbn;

  f32x4 acc[8][4] = {};

  const int srow = t >> 3;
  const int scol = ((t & 7) ^ (srow & 7)) << 3;
  const size_t koff = (size_t)kp * Klen;
  const bf16* Ab = A + (size_t)(bm * 256 + srow) * ldk + koff + scol;
  const bf16* Bb = Bt + (size_t)(bn * 256 + srow) * ldk + koff + scol;
  const size_t r64 = (size_t)64 * ldk;

  auto stage_a = [&](int buf, int h, int kt) {
    const bf16* g = Ab + (size_t)h * 128 * ldk + (size_t)kt * 64;
    gload16(g, &As[buf][h * 8192 + w * 512]);
    gload16(g + r64, &As[buf][h * 8192 + 4096 + w * 512]);
  };
  auto stage_b = [&](int buf, int h, int kt) {
    const bf16* g = Bb + (size_t)h * 128 * ldk + (size_t)kt * 64;
    gload16(g, &Bs[buf][h * 8192 + w * 512]);
    gload16(g + r64, &Bs[buf][h * 8192 + 4096 + w * 512]);
  };

  const int arow = wm * 64 + (lane & 15);
  const int brow = wn * 64 + (lane & 15);
  const int ach0 = (((lane >> 4) + 0) ^ (lane & 7)) << 3;
  const int ach1 = (((lane >> 4) + 4) ^ (lane & 7)) << 3;

  stage_a(0, 0, 0); stage_b(0, 0, 0); stage_b(0, 1, 0); stage_a(0, 1, 0);
  stage_a(1, 0, 1); stage_b(1, 0, 1);
  asm volatile("s_waitcnt vmcnt(4)" ::: "memory");
  GBAR();

  const int NT = Klen >> 6, NI = NT >> 1;
  bf16x8 af[4][2], bf0[2][2], bf1[2][2];

  for (int j = 0; j < NI; ++j) {
    const int tA = 2 * j, tB = 2 * j + 1;
    const bool notlast = (j + 1 < NI);

    LOADA(0, 0);
    LOADB(bf0, 0, 0);
    stage_b(1, 1, tB);
    GBAR();
    MFMA_PH(0, 0, bf0);
    GBAR();
    LOADB(bf1, 1, 0);
    stage_a(1, 1, tB);
    GBAR();
    MFMA_PH(0, 1, bf1);
    GBAR();
    LOADA(1, 0);
    if (notlast) stage_a(0, 0, tA + 2);
    GBAR();
    MFMA_PH(1, 0, bf0);
    GBAR();
    if (notlast) {
      stage_b(0, 0, tA + 2);
      asm volatile("s_waitcnt vmcnt(4)" ::: "memory");
    } else {
      asm volatile("s_waitcnt vmcnt(0)" ::: "memory");
    }
    GBAR();
    MFMA_PH(1, 1, bf1);
    GBAR();

    LOADA(0, 1);
    LOADB(bf0, 0, 1);
    if (notlast) stage_b(0, 1, tA + 2);
    GBAR();
    MFMA_PH(0, 0, bf0);
    GBAR();
    LOADB(bf1, 1, 1);
    if (notlast) stage_a(0, 1, tA + 2);
    GBAR();
    MFMA_PH(0, 1, bf1);
    GBAR();
    LOADA(1, 1);
    if (notlast) stage_a(1, 0, tB + 2);
    GBAR();
    MFMA_PH(1, 0, bf0);
    GBAR();
    if (notlast) {
      stage_b(1, 0, tB + 2);
      asm volatile("s_waitcnt vmcnt(4)" ::: "memory");
    }
    GBAR();
    MFMA_PH(1, 1, bf1);
    GBAR();
  }

#pragma unroll
  for (int am = 0; am < 8; ++am) {
    const int grow0 =
        bm * 256 + (am >> 2) * 128 + wm * 64 + (am & 3) * 16 + (lane >> 4) * 4;
#pragma unroll
    for (int an = 0; an < 4; ++an) {
      const int gcol = bn * 256 + wn * 64 + an * 16 + (lane & 15);
      const float bv = (kp == 0) ? bias[gcol] : 0.f;
#pragma unroll
      for (int r = 0; r < 4; ++r) {
        float v = acc[am][an][r] + bv;
        if (EPI == 2) v = fast_gelu(v);
        const size_t idx = (size_t)(grow0 + r) * N + gcol + kp * kpstride;
        if (EPI == 0) ((float*)Cout)[idx] = v;
        else ((bf16*)Cout)[idx] = (bf16)v;
      }
    }
  }
}

// ---------------------------------------------------------------------------
// Flash attention v2 — swapped-operand 32x32 MFMA, in-register softmax.
// log2-domain (Q pre-scaled by 0.125*log2e; exp2f = native v_exp) +
// defer-max (T13, THR=8 log2-units -> P <= 256, f32/bf16-safe).
// ---------------------------------------------------------------------------
__global__ __launch_bounds__(256, 4) void attn_v2(
    const bf16* __restrict__ qkv, bf16* __restrict__ obuf) {
  __shared__ bf16 Ks[2][4096];
  __shared__ bf16 Vt[2][4096];
  const int t = threadIdx.x, lane = t & 63, w = t >> 6;
  const int g = lane >> 5, q32 = lane & 31, rq7 = q32 & 7;

  const int xcd = blockIdx.x & 7, slot = blockIdx.x >> 3;
  const int work = xcd * 120 + slot;
  const int sbh = work >> 3, qt = work & 7;
  const int sb = sbh / NH, h = sbh % NH;
  const size_t tokbase = (size_t)sb * SEQ;
  const int qoff = h * 64, koff = CD + h * 64, voff = 2 * CD + h * 64;

  const int qrow = qt * 128 + w * 32 + q32;
  bf16x8 qf[4];
  {
    const bf16* qp = qkv + (tokbase + qrow) * NQKV + qoff + g * 8;
#pragma unroll
    for (int kd = 0; kd < 4; ++kd) {
      bf16x8 v = *(const bf16x8*)(qp + kd * 16);
#pragma unroll
      for (int j = 0; j < 8; ++j)
        v[j] = (bf16)((float)v[j] * 0.18033688f);  // 0.125 * log2(e)
      qf[kd] = v;
    }
  }

  const int skv1 = t >> 3, sc1 = (t & 7) ^ (skv1 & 7);
  const int skv2 = (t + 256) >> 3, sc2 = (t & 7) ^ (skv2 & 7);
  const int vkv0 = 2 * (t & 31);
  const int vd0 = 8 * (t >> 5);
  const int c0 = (vkv0 & 51) | ((vkv0 & 4) << 1) | ((vkv0 & 8) >> 1);
  const int vchunk = c0 >> 3, vsub = c0 & 7;
  const bf16* kbase = qkv + tokbase * NQKV + koff;
  const bf16* vbase = qkv + tokbase * NQKV + voff;

  {
    const bf16* kb0 = kbase;
    gload16(kb0 + (size_t)skv1 * NQKV + sc1 * 8, &Ks[0][w * 512]);
    gload16(kb0 + (size_t)skv2 * NQKV + sc2 * 8, &Ks[0][2048 + w * 512]);
    const bf16* vp = vbase + (size_t)vkv0 * NQKV + vd0;
    bf16x8 r0 = *(const bf16x8*)vp;
    bf16x8 r1 = *(const bf16x8*)(vp + NQKV);
#pragma unroll
    for (int j = 0; j < 8; ++j) {
      const int d = vd0 + j;
      *(unsigned*)&Vt[0][d * 64 + ((vchunk ^ j) << 3) + vsub] =
          pack2(r0[j], r1[j]);
    }
  }
  __syncthreads();

  float m_run = -1e30f, l_run = 0.f;
  f32x16 oT0 = {}, oT1 = {};
  int cur = 0;

  for (int kt = 0; kt < 16; ++kt) {
    bf16x8 nv0, nv1;
    if (kt < 15) {
      const bf16* vp = vbase + (size_t)((kt + 1) * 64 + vkv0) * NQKV + vd0;
      nv0 = *(const bf16x8*)vp;
      nv1 = *(const bf16x8*)(vp + NQKV);
      const bf16* kb0 = kbase + (size_t)(kt + 1) * 64 * NQKV;
      gload16(kb0 + (size_t)skv1 * NQKV + sc1 * 8, &Ks[cur ^ 1][w * 512]);
      gload16(kb0 + (size_t)skv2 * NQKV + sc2 * 8,
              &Ks[cur ^ 1][2048 + w * 512]);
    }

    f32x16 sT0 = {}, sT1 = {};
#pragma unroll
    for (int kd = 0; kd < 4; ++kd) {
      bf16x8 kf0 =
          *(const bf16x8*)&Ks[cur][q32 * 64 + (((2 * kd + g) ^ rq7) << 3)];
      bf16x8 kf1 = *(const bf16x8*)&Ks[cur][(32 + q32) * 64 +
                                            (((2 * kd + g) ^ rq7) << 3)];
      sT0 = mfma32(kf0, qf[kd], sT0);
      sT1 = mfma32(kf1, qf[kd], sT1);
    }

    float mt = sT0[0];
#pragma unroll
    for (int r = 1; r < 16; ++r) mt = fmaxf(mt, sT0[r]);
#pragma unroll
    for (int r = 0; r < 16; ++r) mt = fmaxf(mt, sT1[r]);
    mt = fmaxf(mt, __shfl_xor(mt, 32));
    // defer-max: only rescale when the running max grew by > 8 (log2 units)
    if (!__all(mt - m_run <= 8.f)) {
      const float mnew = fmaxf(m_run, mt);
      const float alpha = exp2f(m_run - mnew);
      l_run *= alpha;
#pragma unroll
      for (int r = 0; r < 16; ++r) { oT0[r] *= alpha; oT1[r] *= alpha; }
      m_run = mnew;
    }
    float rs = 0.f;
#pragma unroll
    for (int r = 0; r < 16; ++r) {
      sT0[r] = exp2f(sT0[r] - m_run);
      rs += sT0[r];
    }
#pragma unroll
    for (int r = 0; r < 16; ++r) {
      sT1[r] = exp2f(sT1[r] - m_run);
      rs += sT1[r];
    }
    rs += __shfl_xor(rs, 32);
    l_run += rs;

    bf16x8 pa[4];
#pragma unroll
    for (int hh = 0; hh < 2; ++hh)
#pragma unroll
      for (int j = 0; j < 8; ++j) {
        pa[hh][j] = (bf16)sT0[8 * hh + j];
        pa[2 + hh][j] = (bf16)sT1[8 * hh + j];
      }

#pragma unroll
    for (int ks = 0; ks < 4; ++ks) {
      bf16x8 vf0 =
          *(const bf16x8*)&Vt[cur][q32 * 64 + (((2 * ks + g) ^ rq7) << 3)];
      bf16x8 vf1 = *(const bf16x8*)&Vt[cur][(32 + q32) * 64 +
                                            (((2 * ks + g) ^ rq7) << 3)];
      oT0 = mfma32(vf0, pa[ks], oT0);
      oT1 = mfma32(vf1, pa[ks], oT1);
    }

    if (kt < 15) {
#pragma unroll
      for (int j = 0; j < 8; ++j) {
        const int d = vd0 + j;
        *(unsigned*)&Vt[cur ^ 1][d * 64 + ((vchunk ^ j) << 3) + vsub] =
            pack2(nv0[j], nv1[j]);
      }
    }
    __syncthreads();
    cur ^= 1;
  }

  const float rl = 1.f / l_run;
  bf16* orow = obuf + (tokbase + qrow) * CD + h * 64;
#pragma unroll
  for (int m = 0; m < 4; ++m) {
    bf16x4 o0, o1;
#pragma unroll
    for (int r = 0; r < 4; ++r) {
      o0[r] = (bf16)(oT0[4 * m + r] * rl);
      o1[r] = (bf16)(oT1[4 * m + r] * rl);
    }
    *(bf16x4*)(orow + 8 * m + 4 * g) = o0;
    *(bf16x4*)(orow + 32 + 8 * m + 4 * g) = o1;
  }
}

// ---------------------------------------------------------------------------
// Adapter: out = ((X@dw+db)@mw+mb)@uw+ub ; X bf16 [TOK][768], out bf16.
// (standalone, coalesced dw access: lane owns cols lane+64*i)
// ---------------------------------------------------------------------------
__global__ __launch_bounds__(256) void adapter_kernel(
    const bf16* __restrict__ X, const float* __restrict__ dw,
    const float* __restrict__ db, const float* __restrict__ mw,
    const float* __restrict__ mb, const float* __restrict__ uw,
    const float* __restrict__ ub, bf16* __restrict__ out) {
  const int tok = blockIdx.x * 4 + (threadIdx.x >> 6);
  const int lane = threadIdx.x & 63;
  const bf16* xr = X + (size_t)tok * CD;
  float xv[12];
#pragma unroll
  for (int i = 0; i < 12; ++i) xv[i] = (float)xr[lane + 64 * i];
  float h1[8] = {0, 0, 0, 0, 0, 0, 0, 0};
#pragma unroll
  for (int i = 0; i < 12; ++i) {
    const f32x4* dr = (const f32x4*)(dw + (size_t)(lane + 64 * i) * 8);
    f32x4 d0 = dr[0], d1 = dr[1];
#pragma unroll
    for (int j = 0; j < 4; ++j) {
      h1[j] += xv[i] * d0[j];
      h1[4 + j] += xv[i] * d1[j];
    }
  }
#pragma unroll
  for (int m = 1; m < 64; m <<= 1)
#pragma unroll
    for (int j = 0; j < 8; ++j) h1[j] += __shfl_xor(h1[j], m);
#pragma unroll
  for (int j = 0; j < 8; ++j) h1[j] += db[j];
  float h2[8];
#pragma unroll
  for (int k = 0; k < 8; ++k) {
    float v = mb[k];
#pragma unroll
    for (int j = 0; j < 8; ++j) v += h1[j] * mw[j * 8 + k];
    h2[k] = v;
  }
#pragma unroll
  for (int i = 0; i < 12; ++i) {
    const int c = lane + 64 * i;
    float v = ub[c];
#pragma unroll
    for (int k = 0; k < 8; ++k) v += h2[k] * uw[k * CD + c];
    out[(size_t)tok * CD + c] = (bf16)v;
  }
}

// ---------------------------------------------------------------------------
// Final: z[s] = ys[s](bf16) + m0[s] + m1[s] + cross(a2)   (out f32)
// ---------------------------------------------------------------------------
__global__ __launch_bounds__(256) void cross_residual(
    const bf16* __restrict__ ys, const bf16* __restrict__ m01,
    const bf16* __restrict__ a, float* __restrict__ out) {
  const int s = blockIdx.y;
  const size_t i = (size_t)blockIdx.x * 256 + threadIdx.x;  // group-of-4 index
  const size_t spitch = (size_t)2048 * 768 / 4;
  const size_t sb = (size_t)s * spitch;
  const size_t mstride = (size_t)TOK * CD / 4;
  f32x4 v = b4tof(ys + (sb + i) * 4);
  v += b4tof(m01 + (sb + i) * 4);
  v += b4tof(m01 + (mstride + sb + i) * 4);
  if (s > 0) v += b4tof(a + (sb - spitch + i) * 4);
  if (s < 4) v += b4tof(a + (sb + spitch + i) * 4);
  ((f32x4*)out)[sb + i] = v;
}

// ---------------------------------------------------------------------------
// workspace layout (bytes; ~203 MB)
// ---------------------------------------------------------------------------
#define OFF_WTQKV  ((size_t)0)           // bf16 [2304][768]
#define OFF_WTPROJ ((size_t)3538944)     // bf16 [768][768]
#define OFF_WTFC1  ((size_t)4718592)     // bf16 [3072][768]
#define OFF_WTFC2  ((size_t)9437184)     // bf16 [768][3072]
#define OFF_N1     ((size_t)14155776)    // bf16 [10240][768]; later ln1(ys)
#define OFF_BIG    ((size_t)29884416)    // bf16 qkv [10240][2304]; later h
#define OFF_OBUF   ((size_t)77070336)    // bf16 o [10240][768]
#define OFF_AOM    ((size_t)92798976)    // bf16 partial pairs (proj, then fc2)
#define OFF_A12    ((size_t)124256256)   // bf16 [10240][768]: a1, later a2
#define OFF_YS     ((size_t)155713536)   // bf16 [10240][768] ys
#define OFF_L2Y    ((size_t)187170816)   // bf16 [10240][768]

extern "C" void kernel_launch(void* const* d_in, const int* in_sizes, int n_in,
                              void* d_out, int out_size, void* d_ws,
                              size_t ws_size, hipStream_t stream) {
  const float* x0 = (const float*)d_in[0];
  const float* x1 = (const float*)d_in[1];
  const float* x2 = (const float*)d_in[2];
  const float* x3 = (const float*)d_in[3];
  const float* x4 = (const float*)d_in[4];
  const float* ln1_g = (const float*)d_in[5];
  const float* ln1_b = (const float*)d_in[6];
  const float* ln2_g = (const float*)d_in[7];
  const float* ln2_b = (const float*)d_in[8];
  const float* qkv_w = (const float*)d_in[9];
  const float* qkv_b = (const float*)d_in[10];
  const float* proj_w = (const float*)d_in[11];
  const float* proj_b = (const float*)d_in[12];
  const float* fc1_w = (const float*)d_in[13];
  const float* fc1_b = (const float*)d_in[14];
  const float* fc2_w = (const float*)d_in[15];
  const float* fc2_b = (const float*)d_in[16];
  const float* at_dw = (const float*)d_in[17];
  const float* at_db = (const float*)d_in[18];
  const float* at_mw = (const float*)d_in[19];
  const float* at_mb = (const float*)d_in[20];
  const float* at_uw = (const float*)d_in[21];
  const float* at_ub = (const float*)d_in[22];
  const float* a2_dw = (const float*)d_in[23];
  const float* a2_db = (const float*)d_in[24];
  const float* a2_mw = (const float*)d_in[25];
  const float* a2_mb = (const float*)d_in[26];
  const float* a2_uw = (const float*)d_in[27];
  const float* a2_ub = (const float*)d_in[28];

  char* ws = (char*)d_ws;
  bf16* wt_qkv = (bf16*)(ws + OFF_WTQKV);
  bf16* wt_proj = (bf16*)(ws + OFF_WTPROJ);
  bf16* wt_fc1 = (bf16*)(ws + OFF_WTFC1);
  bf16* wt_fc2 = (bf16*)(ws + OFF_WTFC2);
  bf16* n1 = (bf16*)(ws + OFF_N1);
  bf16* qkvb = (bf16*)(ws + OFF_BIG);
  bf16* obuf = (bf16*)(ws + OFF_OBUF);
  bf16* mbuf = (bf16*)(ws + OFF_AOM);  // split-K bf16 partial pair
  bf16* a12 = (bf16*)(ws + OFF_A12);
  bf16* ysb = (bf16*)(ws + OFF_YS);
  bf16* l2y = (bf16*)(ws + OFF_L2Y);

  const dim3 b256(256);
  const dim3 b512(512);

  // 1. all weight convert+transposes in one launch (6912 tiles)
  transpose_all<<<6912, b256, 0, stream>>>(qkv_w, proj_w, fc1_w, fc2_w,
                                           wt_qkv, wt_proj, wt_fc1, wt_fc2);

  // 2. n1 = LN(xs)  (bf16)
  ln5_kernel<<<2560, b256, 0, stream>>>(x0, x1, x2, x3, x4, ln1_g, ln1_b, n1);

  // 3. qkv = n1 @ qkv_w + qkv_b  (bf16)   grid 40*9=360
  gemm256<1><<<360, b512, 0, stream>>>(n1, wt_qkv, qkv_b, qkvb, NQKV, 768, 768,
                                       9, 360, 0);

  // 4. a1 = adapter(n1)  (bf16)
  adapter_kernel<<<2560, b256, 0, stream>>>(n1, at_dw, at_db, at_mw, at_mb,
                                            at_uw, at_ub, a12);

  // 5. attention -> o (bf16)
  attn_v2<<<960, b256, 0, stream>>>(qkvb, obuf);

  // 6. ao = o @ proj_w + proj_b  — split-K=2, bf16 partials (grid 240)
  gemm256<1><<<240, b512, 0, stream>>>(obuf, wt_proj, proj_b, mbuf, CD, 384,
                                       768, 3, 120, (size_t)TOK * CD);

  // 7+8. ys = xs + (ao0+ao1) + cross(a1) (bf16); ln1(ys)->n1, ln2(ys)->l2y
  fuse_res_ln<<<2560, b256, 0, stream>>>(x0, x1, x2, x3, x4, mbuf, a12, ysb,
                                         ln1_g, ln1_b, ln2_g, ln2_b, n1, l2y);

  // 9. a2 = adapter(ln1(ys))  (bf16, overwrites a1)
  adapter_kernel<<<2560, b256, 0, stream>>>(n1, a2_dw, a2_db, a2_mw, a2_mb,
                                            a2_uw, a2_ub, a12);

  // 10. h = gelu(ln2(ys) @ fc1_w + fc1_b)  (bf16)   grid 40*12=480
  gemm256<2><<<480, b512, 0, stream>>>(l2y, wt_fc1, fc1_b, qkvb, NHID, 768,
                                       768, 12, 480, 0);

  // 11. m = h @ fc2_w + fc2_b  — split-K=2, bf16 partials m0,m1
  gemm256<1><<<240, b512, 0, stream>>>(qkvb, wt_fc2, fc2_b, mbuf, CD, 1536,
                                       3072, 3, 120, (size_t)TOK * CD);

  // 12. z = ys + (m0+m1) + cross(a2) -> d_out
  cross_residual<<<dim3(1536, 5), b256, 0, stream>>>(ysb, mbuf, a12,
                                                     (float*)d_out);
}

// Round 14
// 358.301 us; speedup vs baseline: 1.1129x; 1.0304x over previous
//
#include <hip/hip_runtime.h>
#include <math.h>

// ---------------------------------------------------------------------------
// Shapes: 5 streams x B=2 x N=1024 x C=768; H=12 heads x D=64; AD=8; HID=3072
// TOK = 5*2*1024 = 10240 rows everywhere.
// ---------------------------------------------------------------------------
typedef __bf16 bf16;
typedef __attribute__((ext_vector_type(8))) __bf16 bf16x8;
typedef __attribute__((ext_vector_type(4))) __bf16 bf16x4;
typedef __attribute__((ext_vector_type(4))) float f32x4;
typedef __attribute__((ext_vector_type(16))) float f32x16;

#define TOK   10240
#define CD    768
#define NQKV  2304
#define NHID  3072
#define SEQ   1024
#define NH    12

__device__ __forceinline__ f32x4 mfma16(bf16x8 a, bf16x8 b, f32x4 c) {
  return __builtin_amdgcn_mfma_f32_16x16x32_bf16(a, b, c, 0, 0, 0);
}
__device__ __forceinline__ f32x16 mfma32(bf16x8 a, bf16x8 b, f32x16 c) {
  return __builtin_amdgcn_mfma_f32_32x32x16_bf16(a, b, c, 0, 0, 0);
}

// async global->LDS, 16B per lane. LDS dest must be wave-uniform base;
// HW writes at base + lane*16. Global src is per-lane.
__device__ __forceinline__ void gload16(const void* g, void* l) {
  __builtin_amdgcn_global_load_lds(
      (const __attribute__((address_space(1))) void*)g,
      (__attribute__((address_space(3))) void*)l, 16, 0, 0);
}

__device__ __forceinline__ unsigned pack2(bf16 a, bf16 b) {
  union { unsigned short u[2]; unsigned v; } x;
  x.u[0] = __builtin_bit_cast(unsigned short, a);
  x.u[1] = __builtin_bit_cast(unsigned short, b);
  return x.v;
}

__device__ __forceinline__ f32x4 b4tof(const bf16* p) {
  bf16x4 v = *(const bf16x4*)p;
  f32x4 r;
#pragma unroll
  for (int j = 0; j < 4; ++j) r[j] = (float)v[j];
  return r;
}

// tanh-approx GELU (abs err ~3e-3, fine vs 0.11 threshold); __expf is HW exp
__device__ __forceinline__ float fast_gelu(float v) {
  float u = 0.7978845608f * (v + 0.044715f * v * v * v);
  float e = __expf(fminf(2.f * u, 30.f));
  return 0.5f * v * (1.f + (e - 1.f) / (e + 1.f));
}

// ---------------------------------------------------------------------------
// PREP (merged): blocks [0,6912) transpose all 4 weights ([K][N] f32 ->
// [N][K] bf16, 32x32 tiles); blocks [6912,9472) do LN over the 5 stream
// inputs -> bf16 n1 [TOK][768] (4 rows/block, wave per row).
// ---------------------------------------------------------------------------
__global__ __launch_bounds__(256) void prep_kernel(
    const float* __restrict__ qkv_w, const float* __restrict__ proj_w,
    const float* __restrict__ fc1_w, const float* __restrict__ fc2_w,
    bf16* __restrict__ o_qkv, bf16* __restrict__ o_proj,
    bf16* __restrict__ o_fc1, bf16* __restrict__ o_fc2,
    const float* __restrict__ x0, const float* __restrict__ x1,
    const float* __restrict__ x2, const float* __restrict__ x3,
    const float* __restrict__ x4, const float* __restrict__ g,
    const float* __restrict__ b, bf16* __restrict__ nout) {
  __shared__ float tile[32][33];
  if (blockIdx.x < 6912) {
    int bb = blockIdx.x;
    const float* in;
    bf16* out;
    int K, N, tx, ty;
    if (bb < 1728) {
      in = qkv_w; out = o_qkv; K = 768; N = 2304; tx = bb % 72; ty = bb / 72;
    } else if (bb < 2304) {
      bb -= 1728;
      in = proj_w; out = o_proj; K = 768; N = 768; tx = bb % 24; ty = bb / 24;
    } else if (bb < 4608) {
      bb -= 2304;
      in = fc1_w; out = o_fc1; K = 768; N = 3072; tx = bb % 96; ty = bb / 96;
    } else {
      bb -= 4608;
      in = fc2_w; out = o_fc2; K = 3072; N = 768; tx = bb % 24; ty = bb / 24;
    }
    const int bn = tx * 32, bk = ty * 32;
    const int r = threadIdx.x >> 5, c = threadIdx.x & 31;
#pragma unroll
    for (int i = 0; i < 4; ++i)
      tile[r + 8 * i][c] = in[(size_t)(bk + r + 8 * i) * N + bn + c];
    __syncthreads();
#pragma unroll
    for (int i = 0; i < 4; ++i)
      out[(size_t)(bn + r + 8 * i) * K + bk + c] = (bf16)tile[c][r + 8 * i];
    return;
  }
  // ---- LN part ----
  const int w = threadIdx.x >> 6, lane = threadIdx.x & 63;
  const int row = (blockIdx.x - 6912) * 4 + w;
  const int s = row >> 11, rem = row & 2047;
  const float* xp;
  switch (s) {
    case 0: xp = x0; break; case 1: xp = x1; break; case 2: xp = x2; break;
    case 3: xp = x3; break; default: xp = x4; break;
  }
  const f32x4* xr = (const f32x4*)(xp + (size_t)rem * CD);
  f32x4 v[3];
#pragma unroll
  for (int i = 0; i < 3; ++i) v[i] = xr[lane + 64 * i];
  float sum = 0.f;
#pragma unroll
  for (int i = 0; i < 3; ++i)
#pragma unroll
    for (int j = 0; j < 4; ++j) sum += v[i][j];
#pragma unroll
  for (int m = 32; m >= 1; m >>= 1) sum += __shfl_xor(sum, m);
  const float mu = sum * (1.f / 768.f);
  float vs = 0.f;
#pragma unroll
  for (int i = 0; i < 3; ++i)
#pragma unroll
    for (int j = 0; j < 4; ++j) { float d = v[i][j] - mu; vs += d * d; }
#pragma unroll
  for (int m = 32; m >= 1; m >>= 1) vs += __shfl_xor(vs, m);
  const float rstd = rsqrtf(vs * (1.f / 768.f) + 1e-5f);
  bf16* orow = nout + (size_t)row * CD;
#pragma unroll
  for (int i = 0; i < 3; ++i) {
    const int c4 = lane + 64 * i;
    f32x4 gg = ((const f32x4*)g)[c4], bb = ((const f32x4*)b)[c4];
    bf16x4 o;
#pragma unroll
    for (int j = 0; j < 4; ++j)
      o[j] = (bf16)((v[i][j] - mu) * rstd * gg[j] + bb[j]);
    *(bf16x4*)(orow + c4 * 4) = o;
  }
}

// ---------------------------------------------------------------------------
// FUSED: ys = xs + (ao0+ao1 bf16 split-K partials) + cross(a1 bf16);
// write ys (bf16) + ln1(ys),ln2(ys) (bf16).
// ---------------------------------------------------------------------------
__global__ __launch_bounds__(256) void fuse_res_ln(
    const float* __restrict__ x0, const float* __restrict__ x1,
    const float* __restrict__ x2, const float* __restrict__ x3,
    const float* __restrict__ x4, const bf16* __restrict__ m01,
    const bf16* __restrict__ a, bf16* __restrict__ ys,
    const float* __restrict__ g1, const float* __restrict__ b1,
    const float* __restrict__ g2, const float* __restrict__ b2,
    bf16* __restrict__ o1, bf16* __restrict__ o2) {
  const int w = threadIdx.x >> 6, lane = threadIdx.x & 63;
  const int row = blockIdx.x * 4 + w;
  const int s = row >> 11, rem = row & 2047;
  const float* xp;
  switch (s) {
    case 0: xp = x0; break; case 1: xp = x1; break; case 2: xp = x2; break;
    case 3: xp = x3; break; default: xp = x4; break;
  }
  const f32x4* xr = (const f32x4*)(xp + (size_t)rem * CD);
  const bf16* p0 = m01 + (size_t)row * CD;
  const bf16* p1 = m01 + (size_t)TOK * CD + (size_t)row * CD;
  const bf16* am = a + (size_t)(row - 2048) * CD;
  const bf16* ap = a + (size_t)(row + 2048) * CD;
  f32x4 v[3];
#pragma unroll
  for (int i = 0; i < 3; ++i) {
    const int c4 = lane + 64 * i;
    f32x4 t = xr[c4] + b4tof(p0 + c4 * 4) + b4tof(p1 + c4 * 4);
    if (s > 0) t += b4tof(am + c4 * 4);
    if (s < 4) t += b4tof(ap + c4 * 4);
    v[i] = t;
  }
  bf16* yr = ys + (size_t)row * CD;
#pragma unroll
  for (int i = 0; i < 3; ++i) {
    const int c4 = lane + 64 * i;
    bf16x4 yo;
#pragma unroll
    for (int j = 0; j < 4; ++j) yo[j] = (bf16)v[i][j];
    *(bf16x4*)(yr + c4 * 4) = yo;
  }

  float sum = 0.f;
#pragma unroll
  for (int i = 0; i < 3; ++i)
#pragma unroll
    for (int j = 0; j < 4; ++j) sum += v[i][j];
#pragma unroll
  for (int m = 32; m >= 1; m >>= 1) sum += __shfl_xor(sum, m);
  const float mu = sum * (1.f / 768.f);
  float vs = 0.f;
#pragma unroll
  for (int i = 0; i < 3; ++i)
#pragma unroll
    for (int j = 0; j < 4; ++j) { float d = v[i][j] - mu; vs += d * d; }
#pragma unroll
  for (int m = 32; m >= 1; m >>= 1) vs += __shfl_xor(vs, m);
  const float rstd = rsqrtf(vs * (1.f / 768.f) + 1e-5f);
  bf16* r1 = o1 + (size_t)row * CD;
  bf16* r2 = o2 + (size_t)row * CD;
#pragma unroll
  for (int i = 0; i < 3; ++i) {
    const int c4 = lane + 64 * i;
    f32x4 gg1 = ((const f32x4*)g1)[c4], bb1 = ((const f32x4*)b1)[c4];
    f32x4 gg2 = ((const f32x4*)g2)[c4], bb2 = ((const f32x4*)b2)[c4];
    bf16x4 oa, ob;
#pragma unroll
    for (int j = 0; j < 4; ++j) {
      float n = (v[i][j] - mu) * rstd;
      oa[j] = (bf16)(n * gg1[j] + bb1[j]);
      ob[j] = (bf16)(n * gg2[j] + bb2[j]);
    }
    *(bf16x4*)(r1 + c4 * 4) = oa;
    *(bf16x4*)(r2 + c4 * 4) = ob;
  }
}

// ---------------------------------------------------------------------------
// GEMM 256x256, BK=64, 8 waves (2M x 4N), 8-phase schedule (T2+T3+T4+T5).
// Proven-best configuration (fc1 = 88 us measured, R5/R10/R11).
// EPI: 0 = f32 store, 1 = bf16 store, 2 = fast-GELU -> bf16 store
// ---------------------------------------------------------------------------
#define GBAR() __builtin_amdgcn_s_barrier()

#define LOADA(MH, BUF)                                                      \
  _Pragma("unroll") for (int m_ = 0; m_ < 4; ++m_) {                        \
    af[m_][0] =                                                             \
        *(const bf16x8*)&As[BUF][((MH)*128 + arow + m_ * 16) * 64 + ach0];  \
    af[m_][1] =                                                             \
        *(const bf16x8*)&As[BUF][((MH)*128 + arow + m_ * 16) * 64 + ach1];  \
  }

#define LOADB(DST, NH, BUF)                                                 \
  _Pragma("unroll") for (int n_ = 0; n_ < 2; ++n_) {                        \
    DST[n_][0] =                                                            \
        *(const bf16x8*)&Bs[BUF][(brow + (NH)*32 + n_ * 16) * 64 + ach0];   \
    DST[n_][1] =                                                            \
        *(const bf16x8*)&Bs[BUF][(brow + (NH)*32 + n_ * 16) * 64 + ach1];   \
  }

#define MFMA_PH(MH, NH, BF)                                                 \
  __builtin_amdgcn_s_setprio(1);                                            \
  _Pragma("unroll") for (int m_ = 0; m_ < 4; ++m_)                          \
  _Pragma("unroll") for (int n_ = 0; n_ < 2; ++n_) {                        \
    acc[(MH)*4 + m_][(NH)*2 + n_] =                                         \
        mfma16(af[m_][0], BF[n_][0], acc[(MH)*4 + m_][(NH)*2 + n_]);        \
    acc[(MH)*4 + m_][(NH)*2 + n_] =                                         \
        mfma16(af[m_][1], BF[n_][1], acc[(MH)*4 + m_][(NH)*2 + n_]);        \
  }                                                                         \
  __builtin_amdgcn_s_setprio(0);

template <int EPI>
__global__ __launch_bounds__(512, 2) void gemm256(
    const bf16* __restrict__ A, const bf16* __restrict__ Bt,
    const float* __restrict__ bias, void* __restrict__ Cout, int N, int Klen,
    int ldk, int nbn, int bpk, size_t kpstride) {
  __shared__ bf16 As[2][16384];
  __shared__ bf16 Bs[2][16384];
  const int t = threadIdx.x, lane = t & 63, w = t >> 6;
  const int wm = w >> 2, wn = w & 3;

  const int chunkg = gridDim.x >> 3;
  const int wg = (blockIdx.x & 7) * chunkg + (blockIdx.x >> 3);
  const int kp = wg / bpk, rem = wg % bpk;
  const int bm = rem / nbn, bn = rem % nbn;

  f32x4 acc[8][4] = {};

  const int srow = t >> 3;
  const int scol = ((t & 7) ^ (srow & 7)) << 3;
  const size_t koff = (size_t)kp * Klen;
  const bf16* Ab = A + (size_t)(bm * 256 + srow) * ldk + koff + scol;
  const bf16* Bb = Bt + (size_t)(bn * 256 + srow) * ldk + koff + scol;
  const size_t r64 = (size_t)64 * ldk;

  auto stage_a = [&](int buf, int h, int kt) {
    const bf16* g = Ab + (size_t)h * 128 * ldk + (size_t)kt * 64;
    gload16(g, &As[buf][h * 8192 + w * 512]);
    gload16(g + r64, &As[buf][h * 8192 + 4096 + w * 512]);
  };
  auto stage_b = [&](int buf, int h, int kt) {
    const bf16* g = Bb + (size_t)h * 128 * ldk + (size_t)kt * 64;
    gload16(g, &Bs[buf][h * 8192 + w * 512]);
    gload16(g + r64, &Bs[buf][h * 8192 + 4096 + w * 512]);
  };

  const int arow = wm * 64 + (lane & 15);
  const int brow = wn * 64 + (lane & 15);
  const int ach0 = (((lane >> 4) + 0) ^ (lane & 7)) << 3;
  const int ach1 = (((lane >> 4) + 4) ^ (lane & 7)) << 3;

  stage_a(0, 0, 0); stage_b(0, 0, 0); stage_b(0, 1, 0); stage_a(0, 1, 0);
  stage_a(1, 0, 1); stage_b(1, 0, 1);
  asm volatile("s_waitcnt vmcnt(4)" ::: "memory");
  GBAR();

  const int NT = Klen >> 6, NI = NT >> 1;
  bf16x8 af[4][2], bf0[2][2], bf1[2][2];

  for (int j = 0; j < NI; ++j) {
    const int tA = 2 * j, tB = 2 * j + 1;
    const bool notlast = (j + 1 < NI);

    LOADA(0, 0);
    LOADB(bf0, 0, 0);
    stage_b(1, 1, tB);
    GBAR();
    MFMA_PH(0, 0, bf0);
    GBAR();
    LOADB(bf1, 1, 0);
    stage_a(1, 1, tB);
    GBAR();
    MFMA_PH(0, 1, bf1);
    GBAR();
    LOADA(1, 0);
    if (notlast) stage_a(0, 0, tA + 2);
    GBAR();
    MFMA_PH(1, 0, bf0);
    GBAR();
    if (notlast) {
      stage_b(0, 0, tA + 2);
      asm volatile("s_waitcnt vmcnt(4)" ::: "memory");
    } else {
      asm volatile("s_waitcnt vmcnt(0)" ::: "memory");
    }
    GBAR();
    MFMA_PH(1, 1, bf1);
    GBAR();

    LOADA(0, 1);
    LOADB(bf0, 0, 1);
    if (notlast) stage_b(0, 1, tA + 2);
    GBAR();
    MFMA_PH(0, 0, bf0);
    GBAR();
    LOADB(bf1, 1, 1);
    if (notlast) stage_a(0, 1, tA + 2);
    GBAR();
    MFMA_PH(0, 1, bf1);
    GBAR();
    LOADA(1, 1);
    if (notlast) stage_a(1, 0, tB + 2);
    GBAR();
    MFMA_PH(1, 0, bf0);
    GBAR();
    if (notlast) {
      stage_b(1, 0, tB + 2);
      asm volatile("s_waitcnt vmcnt(4)" ::: "memory");
    }
    GBAR();
    MFMA_PH(1, 1, bf1);
    GBAR();
  }

#pragma unroll
  for (int am = 0; am < 8; ++am) {
    const int grow0 =
        bm * 256 + (am >> 2) * 128 + wm * 64 + (am & 3) * 16 + (lane >> 4) * 4;
#pragma unroll
    for (int an = 0; an < 4; ++an) {
      const int gcol = bn * 256 + wn * 64 + an * 16 + (lane & 15);
      const float bv = (kp == 0) ? bias[gcol] : 0.f;
#pragma unroll
      for (int r = 0; r < 4; ++r) {
        float v = acc[am][an][r] + bv;
        if (EPI == 2) v = fast_gelu(v);
        const size_t idx = (size_t)(grow0 + r) * N + gcol + kp * kpstride;
        if (EPI == 0) ((float*)Cout)[idx] = v;
        else ((bf16*)Cout)[idx] = (bf16)v;
      }
    }
  }
}

// ---------------------------------------------------------------------------
// Flash attention v2 — swapped-operand 32x32 MFMA, in-register softmax.
// (exact R11 version: e-domain softmax, no defer-max; 4 blocks/CU)
// ---------------------------------------------------------------------------
__global__ __launch_bounds__(256, 4) void attn_v2(
    const bf16* __restrict__ qkv, bf16* __restrict__ obuf) {
  __shared__ bf16 Ks[2][4096];
  __shared__ bf16 Vt[2][4096];
  const int t = threadIdx.x, lane = t & 63, w = t >> 6;
  const int g = lane >> 5, q32 = lane & 31, rq7 = q32 & 7;

  const int xcd = blockIdx.x & 7, slot = blockIdx.x >> 3;
  const int work = xcd * 120 + slot;
  const int sbh = work >> 3, qt = work & 7;
  const int sb = sbh / NH, h = sbh % NH;
  const size_t tokbase = (size_t)sb * SEQ;
  const int qoff = h * 64, koff = CD + h * 64, voff = 2 * CD + h * 64;

  const int qrow = qt * 128 + w * 32 + q32;
  bf16x8 qf[4];
  {
    const bf16* qp = qkv + (tokbase + qrow) * NQKV + qoff + g * 8;
#pragma unroll
    for (int kd = 0; kd < 4; ++kd) {
      bf16x8 v = *(const bf16x8*)(qp + kd * 16);
#pragma unroll
      for (int j = 0; j < 8; ++j) v[j] = (bf16)((float)v[j] * 0.125f);
      qf[kd] = v;
    }
  }

  const int skv1 = t >> 3, sc1 = (t & 7) ^ (skv1 & 7);
  const int skv2 = (t + 256) >> 3, sc2 = (t & 7) ^ (skv2 & 7);
  const int vkv0 = 2 * (t & 31);
  const int vd0 = 8 * (t >> 5);
  const int c0 = (vkv0 & 51) | ((vkv0 & 4) << 1) | ((vkv0 & 8) >> 1);
  const int vchunk = c0 >> 3, vsub = c0 & 7;
  const bf16* kbase = qkv + tokbase * NQKV + koff;
  const bf16* vbase = qkv + tokbase * NQKV + voff;

  {
    const bf16* kb0 = kbase;
    gload16(kb0 + (size_t)skv1 * NQKV + sc1 * 8, &Ks[0][w * 512]);
    gload16(kb0 + (size_t)skv2 * NQKV + sc2 * 8, &Ks[0][2048 + w * 512]);
    const bf16* vp = vbase + (size_t)vkv0 * NQKV + vd0;
    bf16x8 r0 = *(const bf16x8*)vp;
    bf16x8 r1 = *(const bf16x8*)(vp + NQKV);
#pragma unroll
    for (int j = 0; j < 8; ++j) {
      const int d = vd0 + j;
      *(unsigned*)&Vt[0][d * 64 + ((vchunk ^ j) << 3) + vsub] =
          pack2(r0[j], r1[j]);
    }
  }
  __syncthreads();

  float m_run = -1e30f, l_run = 0.f;
  f32x16 oT0 = {}, oT1 = {};
  int cur = 0;

  for (int kt = 0; kt < 16; ++kt) {
    bf16x8 nv0, nv1;
    if (kt < 15) {
      const bf16* vp = vbase + (size_t)((kt + 1) * 64 + vkv0) * NQKV + vd0;
      nv0 = *(const bf16x8*)vp;
      nv1 = *(const bf16x8*)(vp + NQKV);
      const bf16* kb0 = kbase + (size_t)(kt + 1) * 64 * NQKV;
      gload16(kb0 + (size_t)skv1 * NQKV + sc1 * 8, &Ks[cur ^ 1][w * 512]);
      gload16(kb0 + (size_t)skv2 * NQKV + sc2 * 8,
              &Ks[cur ^ 1][2048 + w * 512]);
    }

    f32x16 sT0 = {}, sT1 = {};
#pragma unroll
    for (int kd = 0; kd < 4; ++kd) {
      bf16x8 kf0 =
          *(const bf16x8*)&Ks[cur][q32 * 64 + (((2 * kd + g) ^ rq7) << 3)];
      bf16x8 kf1 = *(const bf16x8*)&Ks[cur][(32 + q32) * 64 +
                                            (((2 * kd + g) ^ rq7) << 3)];
      sT0 = mfma32(kf0, qf[kd], sT0);
      sT1 = mfma32(kf1, qf[kd], sT1);
    }

    float mt = sT0[0];
#pragma unroll
    for (int r = 1; r < 16; ++r) mt = fmaxf(mt, sT0[r]);
#pragma unroll
    for (int r = 0; r < 16; ++r) mt = fmaxf(mt, sT1[r]);
    mt = fmaxf(mt, __shfl_xor(mt, 32));
    const float mnew = fmaxf(m_run, mt);
    const float alpha = __expf(m_run - mnew);
    m_run = mnew;
    float rs = 0.f;
#pragma unroll
    for (int r = 0; r < 16; ++r) {
      sT0[r] = __expf(sT0[r] - mnew);
      rs += sT0[r];
    }
#pragma unroll
    for (int r = 0; r < 16; ++r) {
      sT1[r] = __expf(sT1[r] - mnew);
      rs += sT1[r];
    }
    rs += __shfl_xor(rs, 32);
    l_run = l_run * alpha + rs;
#pragma unroll
    for (int r = 0; r < 16; ++r) { oT0[r] *= alpha; oT1[r] *= alpha; }

    bf16x8 pa[4];
#pragma unroll
    for (int hh = 0; hh < 2; ++hh)
#pragma unroll
      for (int j = 0; j < 8; ++j) {
        pa[hh][j] = (bf16)sT0[8 * hh + j];
        pa[2 + hh][j] = (bf16)sT1[8 * hh + j];
      }

#pragma unroll
    for (int ks = 0; ks < 4; ++ks) {
      bf16x8 vf0 =
          *(const bf16x8*)&Vt[cur][q32 * 64 + (((2 * ks + g) ^ rq7) << 3)];
      bf16x8 vf1 = *(const bf16x8*)&Vt[cur][(32 + q32) * 64 +
                                            (((2 * ks + g) ^ rq7) << 3)];
      oT0 = mfma32(vf0, pa[ks], oT0);
      oT1 = mfma32(vf1, pa[ks], oT1);
    }

    if (kt < 15) {
#pragma unroll
      for (int j = 0; j < 8; ++j) {
        const int d = vd0 + j;
        *(unsigned*)&Vt[cur ^ 1][d * 64 + ((vchunk ^ j) << 3) + vsub] =
            pack2(nv0[j], nv1[j]);
      }
    }
    __syncthreads();
    cur ^= 1;
  }

  const float rl = 1.f / l_run;
  bf16* orow = obuf + (tokbase + qrow) * CD + h * 64;
#pragma unroll
  for (int m = 0; m < 4; ++m) {
    bf16x4 o0, o1;
#pragma unroll
    for (int r = 0; r < 4; ++r) {
      o0[r] = (bf16)(oT0[4 * m + r] * rl);
      o1[r] = (bf16)(oT1[4 * m + r] * rl);
    }
    *(bf16x4*)(orow + 8 * m + 4 * g) = o0;
    *(bf16x4*)(orow + 32 + 8 * m + 4 * g) = o1;
  }
}

// ---------------------------------------------------------------------------
// Adapter: out = ((X@dw+db)@mw+mb)@uw+ub ; X bf16 [TOK][768], out bf16.
// (standalone, coalesced dw access: lane owns cols lane+64*i)
// ---------------------------------------------------------------------------
__global__ __launch_bounds__(256) void adapter_kernel(
    const bf16* __restrict__ X, const float* __restrict__ dw,
    const float* __restrict__ db, const float* __restrict__ mw,
    const float* __restrict__ mb, const float* __restrict__ uw,
    const float* __restrict__ ub, bf16* __restrict__ out) {
  const int tok = blockIdx.x * 4 + (threadIdx.x >> 6);
  const int lane = threadIdx.x & 63;
  const bf16* xr = X + (size_t)tok * CD;
  float xv[12];
#pragma unroll
  for (int i = 0; i < 12; ++i) xv[i] = (float)xr[lane + 64 * i];
  float h1[8] = {0, 0, 0, 0, 0, 0, 0, 0};
#pragma unroll
  for (int i = 0; i < 12; ++i) {
    const f32x4* dr = (const f32x4*)(dw + (size_t)(lane + 64 * i) * 8);
    f32x4 d0 = dr[0], d1 = dr[1];
#pragma unroll
    for (int j = 0; j < 4; ++j) {
      h1[j] += xv[i] * d0[j];
      h1[4 + j] += xv[i] * d1[j];
    }
  }
#pragma unroll
  for (int m = 1; m < 64; m <<= 1)
#pragma unroll
    for (int j = 0; j < 8; ++j) h1[j] += __shfl_xor(h1[j], m);
#pragma unroll
  for (int j = 0; j < 8; ++j) h1[j] += db[j];
  float h2[8];
#pragma unroll
  for (int k = 0; k < 8; ++k) {
    float v = mb[k];
#pragma unroll
    for (int j = 0; j < 8; ++j) v += h1[j] * mw[j * 8 + k];
    h2[k] = v;
  }
#pragma unroll
  for (int i = 0; i < 12; ++i) {
    const int c = lane + 64 * i;
    float v = ub[c];
#pragma unroll
    for (int k = 0; k < 8; ++k) v += h2[k] * uw[k * CD + c];
    out[(size_t)tok * CD + c] = (bf16)v;
  }
}

// ---------------------------------------------------------------------------
// Final: z[s] = ys[s](bf16) + m0[s] + m1[s] + cross(a2)   (out f32)
// ---------------------------------------------------------------------------
__global__ __launch_bounds__(256) void cross_residual(
    const bf16* __restrict__ ys, const bf16* __restrict__ m01,
    const bf16* __restrict__ a, float* __restrict__ out) {
  const int s = blockIdx.y;
  const size_t i = (size_t)blockIdx.x * 256 + threadIdx.x;  // group-of-4 index
  const size_t spitch = (size_t)2048 * 768 / 4;
  const size_t sb = (size_t)s * spitch;
  const size_t mstride = (size_t)TOK * CD / 4;
  f32x4 v = b4tof(ys + (sb + i) * 4);
  v += b4tof(m01 + (sb + i) * 4);
  v += b4tof(m01 + (mstride + sb + i) * 4);
  if (s > 0) v += b4tof(a + (sb - spitch + i) * 4);
  if (s < 4) v += b4tof(a + (sb + spitch + i) * 4);
  ((f32x4*)out)[sb + i] = v;
}

// ---------------------------------------------------------------------------
// workspace layout (bytes; ~203 MB)
// ---------------------------------------------------------------------------
#define OFF_WTQKV  ((size_t)0)           // bf16 [2304][768]
#define OFF_WTPROJ ((size_t)3538944)     // bf16 [768][768]
#define OFF_WTFC1  ((size_t)4718592)     // bf16 [3072][768]
#define OFF_WTFC2  ((size_t)9437184)     // bf16 [768][3072]
#define OFF_N1     ((size_t)14155776)    // bf16 [10240][768]; later ln1(ys)
#define OFF_BIG    ((size_t)29884416)    // bf16 qkv [10240][2304]; later h
#define OFF_OBUF   ((size_t)77070336)    // bf16 o [10240][768]
#define OFF_AOM    ((size_t)92798976)    // bf16 partial pairs (proj, then fc2)
#define OFF_A12    ((size_t)124256256)   // bf16 [10240][768]: a1, later a2
#define OFF_YS     ((size_t)155713536)   // bf16 [10240][768] ys
#define OFF_L2Y    ((size_t)187170816)   // bf16 [10240][768]

extern "C" void kernel_launch(void* const* d_in, const int* in_sizes, int n_in,
                              void* d_out, int out_size, void* d_ws,
                              size_t ws_size, hipStream_t stream) {
  const float* x0 = (const float*)d_in[0];
  const float* x1 = (const float*)d_in[1];
  const float* x2 = (const float*)d_in[2];
  const float* x3 = (const float*)d_in[3];
  const float* x4 = (const float*)d_in[4];
  const float* ln1_g = (const float*)d_in[5];
  const float* ln1_b = (const float*)d_in[6];
  const float* ln2_g = (const float*)d_in[7];
  const float* ln2_b = (const float*)d_in[8];
  const float* qkv_w = (const float*)d_in[9];
  const float* qkv_b = (const float*)d_in[10];
  const float* proj_w = (const float*)d_in[11];
  const float* proj_b = (const float*)d_in[12];
  const float* fc1_w = (const float*)d_in[13];
  const float* fc1_b = (const float*)d_in[14];
  const float* fc2_w = (const float*)d_in[15];
  const float* fc2_b = (const float*)d_in[16];
  const float* at_dw = (const float*)d_in[17];
  const float* at_db = (const float*)d_in[18];
  const float* at_mw = (const float*)d_in[19];
  const float* at_mb = (const float*)d_in[20];
  const float* at_uw = (const float*)d_in[21];
  const float* at_ub = (const float*)d_in[22];
  const float* a2_dw = (const float*)d_in[23];
  const float* a2_db = (const float*)d_in[24];
  const float* a2_mw = (const float*)d_in[25];
  const float* a2_mb = (const float*)d_in[26];
  const float* a2_uw = (const float*)d_in[27];
  const float* a2_ub = (const float*)d_in[28];

  char* ws = (char*)d_ws;
  bf16* wt_qkv = (bf16*)(ws + OFF_WTQKV);
  bf16* wt_proj = (bf16*)(ws + OFF_WTPROJ);
  bf16* wt_fc1 = (bf16*)(ws + OFF_WTFC1);
  bf16* wt_fc2 = (bf16*)(ws + OFF_WTFC2);
  bf16* n1 = (bf16*)(ws + OFF_N1);
  bf16* qkvb = (bf16*)(ws + OFF_BIG);
  bf16* obuf = (bf16*)(ws + OFF_OBUF);
  bf16* mbuf = (bf16*)(ws + OFF_AOM);  // split-K bf16 partial pair
  bf16* a12 = (bf16*)(ws + OFF_A12);
  bf16* ysb = (bf16*)(ws + OFF_YS);
  bf16* l2y = (bf16*)(ws + OFF_L2Y);

  const dim3 b256(256);
  const dim3 b512(512);

  // 1. weight transposes (6912 blocks) + ln5 (2560 blocks) in ONE launch
  prep_kernel<<<9472, b256, 0, stream>>>(qkv_w, proj_w, fc1_w, fc2_w, wt_qkv,
                                         wt_proj, wt_fc1, wt_fc2, x0, x1, x2,
                                         x3, x4, ln1_g, ln1_b, n1);

  // 2. qkv = n1 @ qkv_w + qkv_b  (bf16)   grid 40*9=360
  gemm256<1><<<360, b512, 0, stream>>>(n1, wt_qkv, qkv_b, qkvb, NQKV, 768, 768,
                                       9, 360, 0);

  // 3. a1 = adapter(n1)  (bf16)
  adapter_kernel<<<2560, b256, 0, stream>>>(n1, at_dw, at_db, at_mw, at_mb,
                                            at_uw, at_ub, a12);

  // 4. attention -> o (bf16)
  attn_v2<<<960, b256, 0, stream>>>(qkvb, obuf);

  // 5. ao = o @ proj_w + proj_b  — split-K=2, bf16 partials (grid 240)
  gemm256<1><<<240, b512, 0, stream>>>(obuf, wt_proj, proj_b, mbuf, CD, 384,
                                       768, 3, 120, (size_t)TOK * CD);

  // 6. ys = xs + (ao0+ao1) + cross(a1) (bf16); ln1(ys)->n1, ln2(ys)->l2y
  fuse_res_ln<<<2560, b256, 0, stream>>>(x0, x1, x2, x3, x4, mbuf, a12, ysb,
                                         ln1_g, ln1_b, ln2_g, ln2_b, n1, l2y);

  // 7. a2 = adapter(ln1(ys))  (bf16, overwrites a1)
  adapter_kernel<<<2560, b256, 0, stream>>>(n1, a2_dw, a2_db, a2_mw, a2_mb,
                                            a2_uw, a2_ub, a12);

  // 8. h = gelu(ln2(ys) @ fc1_w + fc1_b)  (bf16)   grid 40*12=480
  gemm256<2><<<480, b512, 0, stream>>>(l2y, wt_fc1, fc1_b, qkvb, NHID, 768,
                                       768, 12, 480, 0);

  // 9. m = h @ fc2_w + fc2_b  — split-K=2, bf16 partials m0,m1
  gemm256<1><<<240, b512, 0, stream>>>(qkvb, wt_fc2, fc2_b, mbuf, CD, 1536,
                                       3072, 3, 120, (size_t)TOK * CD);

  // 10. z = ys + (m0+m1) + cross(a2) -> d_out
  cross_residual<<<dim3(1536, 5), b256, 0, stream>>>(ysb, mbuf, a12,
                                                     (float*)d_out);
}